// Round 8
// baseline (341.982 us; speedup 1.0000x reference)
//
#include <hip/hip_runtime.h>
#include <math.h>

#define B_  128
#define N_  21
#define D_  300
#define NPAIRS 231                  // upper-tri incl diag
#define NPAIR_TOT (B_ * NPAIRS)     // 29568
#define GRID_E (NPAIR_TOT / 64)     // 462 blocks x 4 waves x 16 pairs
#define NROWS (B_ * N_)             // 2688
#define DP  320

typedef __attribute__((ext_vector_type(8))) short short8v;
typedef __attribute__((ext_vector_type(4))) float f32x4;

__device__ __forceinline__ float lrelu(float v) { return v > 0.f ? v : 0.01f * v; }

__device__ __forceinline__ unsigned short f2bf(float f) {
    unsigned u = __builtin_bit_cast(unsigned, f);
    u += 0x7FFFu + ((u >> 16) & 1u);
    return (unsigned short)(u >> 16);
}
__device__ __forceinline__ float bf2f(unsigned short h) {
    unsigned u = ((unsigned)h) << 16;
    return __builtin_bit_cast(float, u);
}

// ---------------------------------------------------------------------------
// One prep kernel: edge weights (2 layers) + node weights -> bf16 hi/lo.
__global__ __launch_bounds__(256) void prep_all(
    const float* __restrict__ e00, const float* __restrict__ e01, const float* __restrict__ e02,
    const float* __restrict__ e10, const float* __restrict__ e11, const float* __restrict__ e12,
    const float* __restrict__ n0n, const float* __restrict__ n0r,
    const float* __restrict__ n1n, const float* __restrict__ n1r,
    unsigned short* __restrict__ ewb, unsigned short* __restrict__ nwb, int do_node)
{
    int idx = blockIdx.x * 256 + threadIdx.x;   // grid 2624 -> 671744 exact
    float v; unsigned short *ph, *pl; int off;
    if (idx < 262144) {
        int l = idx >> 17;
        int t = idx & 131071;
        unsigned short* blk = ewb + (size_t)l * 262144;
        const float* w0 = l ? e10 : e00;
        const float* w1 = l ? e11 : e01;
        const float* w2 = l ? e12 : e02;
        if (t < 81920) {
            int n = t / 320, k = t - n * 320;
            v = (k < 300) ? w0[n * 300 + k] : 0.f;
            ph = blk; pl = blk + 81920; off = t;
        } else if (t < 114688) {
            int r = t - 81920; v = w1[r];
            ph = blk + 163840; pl = blk + 196608; off = r;
        } else {
            int r = t - 114688; v = w2[r];
            ph = blk + 229376; pl = blk + 245760; off = r;
        }
    } else {
        if (!do_node) return;
        int t = idx - 262144;                    // 0 .. 409599
        int l = t / 204800;
        int r = t - l * 204800;
        int mat = r / 102400;
        int q = r - mat * 102400;
        int n = q / 320, k = q - n * 320;
        const float* src = l ? (mat ? n1r : n1n) : (mat ? n0r : n0n);
        v = (n < 300 && k < 300) ? src[n * 300 + k] : 0.f;
        unsigned short* blk = nwb + (size_t)l * 409600;
        ph = blk + mat * 204800; pl = ph + 102400; off = q;
    }
    unsigned short hb = f2bf(v);
    ph[off] = hb; pl[off] = f2bf(v - bf2f(hb));
}

// ---------------------------------------------------------------------------
// 4-lane-group transpose (by value, inlined to v_bpermute + cndmask).
__device__ __forceinline__ short8v mk_frag(uint2 tlo, uint2 thi,
                                           int s1, int s2, bool hi)
{
    unsigned a0 = (unsigned)__shfl((int)tlo.x, s1);
    unsigned b0 = (unsigned)__shfl((int)thi.x, s1);
    unsigned a1 = (unsigned)__shfl((int)tlo.y, s1);
    unsigned b1 = (unsigned)__shfl((int)thi.y, s1);
    unsigned a2 = (unsigned)__shfl((int)tlo.x, s2);
    unsigned b2 = (unsigned)__shfl((int)thi.x, s2);
    unsigned a3 = (unsigned)__shfl((int)tlo.y, s2);
    unsigned b3 = (unsigned)__shfl((int)thi.y, s2);
    union { unsigned u[4]; short8v v; } r;
    r.u[0] = hi ? b0 : a0; r.u[1] = hi ? b1 : a1;
    r.u[2] = hi ? b2 : a2; r.u[3] = hi ? b3 : a3;
    return r.v;
}

// ---------------------------------------------------------------------------
// Wave-independent edge MLP: 16 pairs/wave, zero LDS/barriers.
// Key round-8 change: ALL weight fragments of a k-chunk are hoisted into
// chunk-scope arrays -> 32 L2 loads in flight, ONE wait per chunk; the
// exp/cvt VALU work for the next activation fragment sits between load
// issue and use to hide L2 latency.
__global__ __launch_bounds__(256, 2) void edge_mfma(
    const float* __restrict__ x,
    const unsigned short* __restrict__ w0h, const unsigned short* __restrict__ w0l,
    const unsigned short* __restrict__ w1h, const unsigned short* __restrict__ w1l,
    const unsigned short* __restrict__ w2h, const unsigned short* __restrict__ w2l,
    const float* __restrict__ wo, const float* __restrict__ bo,
    float* __restrict__ adjraw)
{
    const int tid  = threadIdx.x;
    const int lane = tid & 63;
    const int w    = tid >> 6;
    const int l15  = lane & 15;
    const int l4   = lane >> 4;

    // this lane-column's pair
    const int p = (blockIdx.x * 4 + w) * 16 + l15;
    int bb = p / NPAIRS;
    int u  = p - bb * NPAIRS;
    int ii = 0;
    while (u >= N_ - ii) { u -= N_ - ii; ++ii; }
    int jj = ii + u;
    const float* xi = x + ((size_t)bb * N_ + ii) * D_;
    const float* xj = x + ((size_t)bb * N_ + jj) * D_;

    const int s1 = (lane & 15) | ((lane & 16) << 1);  // (p, 2*(l4&1))
    const int s2 = s1 + 16;                           // (p, 2*(l4&1)+1)
    const bool hi = (l4 >> 1) != 0;

    // ---------------- G1: h0 = w0 @ xij^T, K=320 ----------------
    f32x4 acc[16];
    #pragma unroll
    for (int t = 0; t < 16; ++t) acc[t] = (f32x4){0.f, 0.f, 0.f, 0.f};

    #pragma unroll 1
    for (int c = 0; c < 10; ++c) {
        const int kg = c * 32 + l4 * 8;
        // 1) hoisted weight loads for the WHOLE chunk: 32 loads in flight
        short8v wh[16], wl[16];
        #pragma unroll
        for (int t = 0; t < 16; ++t) {
            const size_t n = (size_t)(t * 16 + l15);
            wh[t] = *(const short8v*)(w0h + n * 320 + kg);
            wl[t] = *(const short8v*)(w0l + n * 320 + kg);
        }
        // 2) activation fragment (x loads + exp + cvt): VALU work that
        //    overlaps the weight-load latency
        const int d0 = c * 32 + l4 * 8;
        float v[8];
        if (c < 9) {
            float4 a0 = *(const float4*)(xi + d0);
            float4 a1 = *(const float4*)(xi + d0 + 4);
            float4 b0 = *(const float4*)(xj + d0);
            float4 b1 = *(const float4*)(xj + d0 + 4);
            #pragma unroll
            for (int e = 0; e < 4; ++e) {
                v[e]     = expf(-fabsf((&a0.x)[e] - (&b0.x)[e]));
                v[4 + e] = expf(-fabsf((&a1.x)[e] - (&b1.x)[e]));
            }
        } else {
            #pragma unroll
            for (int e = 0; e < 8; ++e) {
                int d = d0 + e;
                v[e] = (d < D_) ? expf(-fabsf(xi[d] - xj[d])) : 0.f;
            }
        }
        short8v bh, bl;
        #pragma unroll
        for (int e = 0; e < 8; ++e) {
            unsigned short hb = f2bf(v[e]);
            bh[e] = (short)hb;
            bl[e] = (short)f2bf(v[e] - bf2f(hb));
        }
        // 3) MFMA the whole chunk (one waitcnt drain above this)
        #pragma unroll
        for (int t = 0; t < 16; ++t) {
            acc[t] = __builtin_amdgcn_mfma_f32_16x16x32_bf16(wh[t], bh, acc[t], 0, 0, 0);
            acc[t] = __builtin_amdgcn_mfma_f32_16x16x32_bf16(wh[t], bl, acc[t], 0, 0, 0);
            acc[t] = __builtin_amdgcn_mfma_f32_16x16x32_bf16(wl[t], bh, acc[t], 0, 0, 0);
        }
    }

    // pack h0 -> bf16 hi/lo (lane keeps chans t*16+l4*4+r for its pair col)
    uint2 hh[16], ll[16];
    #pragma unroll
    for (int t = 0; t < 16; ++t) {
        unsigned short h_[4], l_[4];
        #pragma unroll
        for (int r = 0; r < 4; ++r) {
            float f = lrelu(acc[t][r]);
            h_[r] = f2bf(f);
            l_[r] = f2bf(f - bf2f(h_[r]));
        }
        hh[t].x = (unsigned)h_[0] | ((unsigned)h_[1] << 16);
        hh[t].y = (unsigned)h_[2] | ((unsigned)h_[3] << 16);
        ll[t].x = (unsigned)l_[0] | ((unsigned)l_[1] << 16);
        ll[t].y = (unsigned)l_[2] | ((unsigned)l_[3] << 16);
    }

    // ---------------- G2: h1 = w1 @ h0^T, K=256 ----------------
    f32x4 acc2[8];
    #pragma unroll
    for (int t = 0; t < 8; ++t) acc2[t] = (f32x4){0.f, 0.f, 0.f, 0.f};
    #pragma unroll 1
    for (int ks = 0; ks < 8; ++ks) {
        const int kg = ks * 32 + l4 * 8;
        short8v wh[8], wl[8];
        #pragma unroll
        for (int t = 0; t < 8; ++t) {
            const size_t n = (size_t)(t * 16 + l15);
            wh[t] = *(const short8v*)(w1h + n * 256 + kg);
            wl[t] = *(const short8v*)(w1l + n * 256 + kg);
        }
        // shuffle-transpose overlaps the load latency
        short8v bh = mk_frag(hh[2*ks], hh[2*ks+1], s1, s2, hi);
        short8v bl = mk_frag(ll[2*ks], ll[2*ks+1], s1, s2, hi);
        #pragma unroll
        for (int t = 0; t < 8; ++t) {
            acc2[t] = __builtin_amdgcn_mfma_f32_16x16x32_bf16(wh[t], bh, acc2[t], 0, 0, 0);
            acc2[t] = __builtin_amdgcn_mfma_f32_16x16x32_bf16(wh[t], bl, acc2[t], 0, 0, 0);
            acc2[t] = __builtin_amdgcn_mfma_f32_16x16x32_bf16(wl[t], bh, acc2[t], 0, 0, 0);
        }
    }

    // pack h1
    uint2 hh1[8], ll1[8];
    #pragma unroll
    for (int t = 0; t < 8; ++t) {
        unsigned short h_[4], l_[4];
        #pragma unroll
        for (int r = 0; r < 4; ++r) {
            float f = lrelu(acc2[t][r]);
            h_[r] = f2bf(f);
            l_[r] = f2bf(f - bf2f(h_[r]));
        }
        hh1[t].x = (unsigned)h_[0] | ((unsigned)h_[1] << 16);
        hh1[t].y = (unsigned)h_[2] | ((unsigned)h_[3] << 16);
        ll1[t].x = (unsigned)l_[0] | ((unsigned)l_[1] << 16);
        ll1[t].y = (unsigned)l_[2] | ((unsigned)l_[3] << 16);
    }

    // ---------------- G3: h2 = w2 @ h1^T, K=128 ----------------
    f32x4 acc3[8];
    #pragma unroll
    for (int t = 0; t < 8; ++t) acc3[t] = (f32x4){0.f, 0.f, 0.f, 0.f};
    #pragma unroll 1
    for (int ks = 0; ks < 4; ++ks) {
        const int kg = ks * 32 + l4 * 8;
        short8v wh[8], wl[8];
        #pragma unroll
        for (int t = 0; t < 8; ++t) {
            const size_t n = (size_t)(t * 16 + l15);
            wh[t] = *(const short8v*)(w2h + n * 128 + kg);
            wl[t] = *(const short8v*)(w2l + n * 128 + kg);
        }
        short8v bh = mk_frag(hh1[2*ks], hh1[2*ks+1], s1, s2, hi);
        short8v bl = mk_frag(ll1[2*ks], ll1[2*ks+1], s1, s2, hi);
        #pragma unroll
        for (int t = 0; t < 8; ++t) {
            acc3[t] = __builtin_amdgcn_mfma_f32_16x16x32_bf16(wh[t], bh, acc3[t], 0, 0, 0);
            acc3[t] = __builtin_amdgcn_mfma_f32_16x16x32_bf16(wh[t], bl, acc3[t], 0, 0, 0);
            acc3[t] = __builtin_amdgcn_mfma_f32_16x16x32_bf16(wl[t], bh, acc3[t], 0, 0, 0);
        }
    }

    // ---------------- sim: in-register reduce over 128 channels ------------
    float ps = 0.f;
    #pragma unroll
    for (int t = 0; t < 8; ++t) {
        float4 wov = *(const float4*)(wo + t * 16 + l4 * 4);
        #pragma unroll
        for (int r = 0; r < 4; ++r)
            ps += lrelu(acc3[t][r]) * (&wov.x)[r];
    }
    ps += __shfl_xor(ps, 16);
    ps += __shfl_xor(ps, 32);
    if (l4 == 0) {
        float a = 1.f / (1.f + expf(-(ps + bo[0])));
        if (ii == jj) a = 0.f;
        adjraw[(size_t)bb * 441 + ii * 21 + jj] = a;
        adjraw[(size_t)bb * 441 + jj * 21 + ii] = a;
    }
}

// ---------------------------------------------------------------------------
// top-5 per row (fallback path only)
__global__ __launch_bounds__(64) void topk_kernel(
    const float* __restrict__ adjraw, float* __restrict__ A)
{
    const int row = blockIdx.x;
    const int lane = threadIdx.x;
    __shared__ float sadj[32];
    __shared__ unsigned s_used;
    if (lane < N_) sadj[lane] = adjraw[row * N_ + lane];
    __syncthreads();
    if (lane == 0) {
        unsigned used = 0;
        for (int r = 0; r < 5; ++r) {
            float best = -1.f; int bi = 0;
            for (int j = 0; j < N_; ++j) {
                if (used & (1u << j)) continue;
                if (sadj[j] > best) { best = sadj[j]; bi = j; }
            }
            used |= (1u << bi);
        }
        s_used = used;
    }
    __syncthreads();
    if (lane < N_)
        A[row * N_ + lane] = ((s_used >> lane) & 1u) ? sadj[lane] : 0.f;
}

// ---------------------------------------------------------------------------
// Node GEMM via MFMA: P = x@wn^T and R = x@wr^T, M=2688 rows.
__global__ __launch_bounds__(256, 4) void node_gemm(
    const float* __restrict__ xin,
    const unsigned short* __restrict__ wnh, const unsigned short* __restrict__ wnl,
    const unsigned short* __restrict__ wrh, const unsigned short* __restrict__ wrl,
    float* __restrict__ nbuf)
{
    __shared__ __align__(16) unsigned short sxh[2][512], sxl[2][512];

    const int tid  = threadIdx.x;
    const int lane = tid & 63;
    const int w    = tid >> 6;
    const int l15  = lane & 15;
    const int l4   = lane >> 4;
    const int M0   = blockIdx.x * 16;
    const int mat  = blockIdx.y;

    const unsigned short* ah_base = mat ? wrh : wnh;
    const unsigned short* al_base = mat ? wrl : wnl;
    float* ob = nbuf + (size_t)mat * NROWS * DP;

    const int sm = tid >> 4;
    const int sk = (tid & 15) * 2;
    const float* xrow = xin + (size_t)(M0 + sm) * D_;
    const int sa = sm * 32 + (((sk >> 3) ^ ((sm >> 1) & 3)) << 3) + (sk & 7);
    const int xr_off = l15 * 32 + ((l4 ^ ((l15 >> 1) & 3)) << 3);

    f32x4 acc[5];
    #pragma unroll
    for (int t = 0; t < 5; ++t) acc[t] = (f32x4){0.f, 0.f, 0.f, 0.f};

    {
        float2 v = *(const float2*)(xrow + sk);
        unsigned short h0 = f2bf(v.x), h1 = f2bf(v.y);
        unsigned uh = (unsigned)h0 | ((unsigned)h1 << 16);
        unsigned ul = (unsigned)f2bf(v.x - bf2f(h0)) |
                      ((unsigned)f2bf(v.y - bf2f(h1)) << 16);
        *(unsigned*)(&sxh[0][sa]) = uh;
        *(unsigned*)(&sxl[0][sa]) = ul;
    }
    __syncthreads();

    #pragma unroll 1
    for (int c = 0; c < 10; ++c) {
        const int sel = c & 1;
        short8v wh[5], wl[5];
        const int kg = c * 32 + l4 * 8;
        #pragma unroll
        for (int t = 0; t < 5; ++t) {
            const size_t n = (size_t)((w * 5 + t) * 16 + l15);
            wh[t] = *(const short8v*)(ah_base + n * DP + kg);
            wl[t] = *(const short8v*)(al_base + n * DP + kg);
        }
        float2 xv; bool have = false;
        if (c < 9) {
            const int k0 = (c + 1) * 32 + sk;
            if (k0 < D_) { xv = *(const float2*)(xrow + k0); have = true; }
        }
        short8v bh = *(const short8v*)(sxh[sel] + xr_off);
        short8v bl = *(const short8v*)(sxl[sel] + xr_off);
        #pragma unroll
        for (int t = 0; t < 5; ++t) {
            acc[t] = __builtin_amdgcn_mfma_f32_16x16x32_bf16(wh[t], bh, acc[t], 0, 0, 0);
            acc[t] = __builtin_amdgcn_mfma_f32_16x16x32_bf16(wh[t], bl, acc[t], 0, 0, 0);
            acc[t] = __builtin_amdgcn_mfma_f32_16x16x32_bf16(wl[t], bh, acc[t], 0, 0, 0);
        }
        if (c < 9) {
            unsigned uh = 0, ul = 0;
            if (have) {
                unsigned short h0 = f2bf(xv.x), h1 = f2bf(xv.y);
                uh = (unsigned)h0 | ((unsigned)h1 << 16);
                ul = (unsigned)f2bf(xv.x - bf2f(h0)) |
                     ((unsigned)f2bf(xv.y - bf2f(h1)) << 16);
            }
            *(unsigned*)(&sxh[sel ^ 1][sa]) = uh;
            *(unsigned*)(&sxl[sel ^ 1][sa]) = ul;
        }
        __syncthreads();
    }

    #pragma unroll
    for (int t = 0; t < 5; ++t) {
        const int n0 = (w * 5 + t) * 16 + l4 * 4;
        float4 v;
        v.x = acc[t][0]; v.y = acc[t][1]; v.z = acc[t][2]; v.w = acc[t][3];
        *(float4*)(ob + (size_t)(M0 + l15) * DP + n0) = v;
    }
}

// ---------------------------------------------------------------------------
// Fused top-k + combine: out = lrelu((A@P + rs*(bn+e0))*0.2 + R + br)
__global__ __launch_bounds__(256) void node_combine(
    const float* __restrict__ adjraw, const float* __restrict__ nbuf,
    const float* __restrict__ bn, const float* __restrict__ br,
    const float* __restrict__ eemb, float* __restrict__ out)
{
    const int row = blockIdx.x;           // 0..2687
    const int b = row / N_;
    const int tid = threadIdx.x;
    __shared__ float sadj[24];
    __shared__ float sA[24];
    __shared__ float s_rs;
    if (tid < N_) sadj[tid] = adjraw[(size_t)row * N_ + tid];
    __syncthreads();
    if (tid == 0) {
        unsigned used = 0;
        for (int r = 0; r < 5; ++r) {
            float best = -1.f; int bi = 0;
            for (int j = 0; j < N_; ++j) {
                if (used & (1u << j)) continue;
                if (sadj[j] > best) { best = sadj[j]; bi = j; }
            }
            used |= (1u << bi);
        }
        float rs = 0.f;
        for (int j = 0; j < N_; ++j) {
            float m = ((used >> j) & 1u) ? sadj[j] : 0.f;
            sA[j] = m; rs += m;
        }
        s_rs = rs;
    }
    __syncthreads();
    const float* Pb = nbuf + (size_t)b * N_ * DP;
    const float* Rr = nbuf + (size_t)NROWS * DP + (size_t)row * DP;
    const float rs = s_rs;
    #pragma unroll
    for (int pass = 0; pass < 2; ++pass) {
        int o = tid + pass * 256;
        if (o < D_) {
            float m = 0.f;
            #pragma unroll
            for (int s = 0; s < N_; ++s) m += sA[s] * Pb[(size_t)s * DP + o];
            out[(size_t)row * D_ + o] =
                lrelu((m + rs * (bn[o] + eemb[o])) * 0.2f + Rr[o] + br[o]);
        }
    }
}

// ---------------------------------------------------------------------------
// Fallback fp32 node kernel (if ws too small for nbuf)
__global__ __launch_bounds__(320) void node_kernel(
    const float* __restrict__ xin, const float* __restrict__ A,
    const float* __restrict__ wn, const float* __restrict__ bn,
    const float* __restrict__ wr, const float* __restrict__ br,
    const float* __restrict__ eemb, float* __restrict__ out)
{
    const int b = blockIdx.x;
    const int tid = threadIdx.x;
    __shared__ float sx[N_][304];
    __shared__ float sA[N_][24];
    __shared__ float srs[N_];

    const float* xb = xin + (size_t)b * N_ * D_;
    for (int it = tid; it < N_ * D_; it += 320) {
        int j = it / D_, d = it - (it / D_) * D_;
        sx[j][d] = xb[it];
    }
    for (int it = tid; it < N_ * N_; it += 320) {
        int t = it / N_, s = it - (it / N_) * N_;
        sA[t][s] = A[((size_t)b * N_ + t) * N_ + s];
    }
    __syncthreads();
    if (tid < N_) {
        float s = 0.f;
        #pragma unroll
        for (int j = 0; j < N_; ++j) s += sA[tid][j];
        srs[tid] = s;
    }
    __syncthreads();

    const int o = tid;
    if (o < D_) {
        float nacc[N_], racc[N_];
        #pragma unroll
        for (int j = 0; j < N_; ++j) { nacc[j] = 0.f; racc[j] = 0.f; }
        const float* wnr = wn + (size_t)o * D_;
        const float* wrr = wr + (size_t)o * D_;
        for (int k4 = 0; k4 < D_; k4 += 4) {
            float4 wn4 = *(const float4*)(wnr + k4);
            float4 wr4 = *(const float4*)(wrr + k4);
            #pragma unroll
            for (int j = 0; j < N_; ++j) {
                float4 xv = *(const float4*)(&sx[j][k4]);
                nacc[j] += wn4.x * xv.x; nacc[j] += wn4.y * xv.y;
                nacc[j] += wn4.z * xv.z; nacc[j] += wn4.w * xv.w;
                racc[j] += wr4.x * xv.x; racc[j] += wr4.y * xv.y;
                racc[j] += wr4.z * xv.z; racc[j] += wr4.w * xv.w;
            }
        }
        const float bn_o = bn[o], br_o = br[o], e0_o = eemb[o];
        const float add_o = bn_o + e0_o;
        #pragma unroll
        for (int t = 0; t < N_; ++t) {
            float m = 0.f;
            #pragma unroll
            for (int s = 0; s < N_; ++s) m += sA[t][s] * nacc[s];
            out[((size_t)b * N_ + t) * D_ + o] =
                lrelu((m + srs[t] * add_o) * 0.2f + racc[t] + br_o);
        }
    }
}

// ---------------------------------------------------------------------------
extern "C" void kernel_launch(void* const* d_in, const int* in_sizes, int n_in,
                              void* d_out, int out_size, void* d_ws, size_t ws_size,
                              hipStream_t stream)
{
    const float* x0 = (const float*)d_in[0];
    auto L = [&](int l, int k) { return (const float*)d_in[1 + l * 10 + k]; };

    // ws layout:
    //   adjraw @0        (225,792)
    //   A      @256KB    (225,792)               (fallback only)
    //   edge w @512KB    (2 x 512KB)             -> ends 1,572,864
    //   node w @1.5MB    (2 x 819,200)           -> ends 3,211,264
    //   nbuf   @3,211,264 (6,881,280)            -> ends 10,092,544
    float* adjraw = (float*)d_ws;
    float* A      = (float*)((char*)d_ws + 262144);
    unsigned short* ewb = (unsigned short*)((char*)d_ws + 524288);
    unsigned short* nwb = (unsigned short*)((char*)d_ws + 1572864);
    float* nbuf   = (float*)((char*)d_ws + 3211264);
    const size_t WS_NEED = 10092544;
    const bool newnode = (ws_size >= WS_NEED);

    prep_all<<<2624, 256, 0, stream>>>(
        L(0,0), L(0,1), L(0,2), L(1,0), L(1,1), L(1,2),
        L(0,5), L(0,7), L(1,5), L(1,7), ewb, nwb, newnode ? 1 : 0);

    for (int l = 0; l < 2; ++l) {
        const float* xin = (l == 0) ? x0 : (const float*)d_out;
        unsigned short* blk = ewb + (size_t)l * 262144;
        edge_mfma<<<GRID_E, 256, 0, stream>>>(xin,
            blk, blk + 81920, blk + 163840, blk + 196608, blk + 229376, blk + 245760,
            L(l, 3), L(l, 4), adjraw);
        if (newnode) {
            unsigned short* nblk = nwb + (size_t)l * 409600;
            node_gemm<<<dim3(NROWS / 16, 2), 256, 0, stream>>>(
                xin, nblk, nblk + 102400, nblk + 204800, nblk + 307200, nbuf);
            node_combine<<<NROWS, 256, 0, stream>>>(adjraw, nbuf, L(l, 6), L(l, 8),
                                                    L(l, 9), (float*)d_out);
        } else {
            topk_kernel<<<NROWS, 64, 0, stream>>>(adjraw, A);
            node_kernel<<<B_, 320, 0, stream>>>(xin, A, L(l, 5), L(l, 6), L(l, 7),
                                                L(l, 8), L(l, 9), (float*)d_out);
        }
    }
}

// Round 9
// 210.444 us; speedup vs baseline: 1.6250x; 1.6250x over previous
//
#include <hip/hip_runtime.h>
#include <math.h>

#define B_  128
#define N_  21
#define D_  300
#define NPAIRS 231                  // upper-tri incl diag
#define NPAIR_TOT (B_ * NPAIRS)     // 29568
#define GRID_E (NPAIR_TOT / 64)     // 462 blocks x 4 waves x 16 pairs
#define NROWS (B_ * N_)             // 2688
#define DP  320

typedef __attribute__((ext_vector_type(8))) short short8v;
typedef __attribute__((ext_vector_type(4))) float f32x4;

__device__ __forceinline__ float lrelu(float v) { return v > 0.f ? v : 0.01f * v; }

__device__ __forceinline__ unsigned short f2bf(float f) {
    unsigned u = __builtin_bit_cast(unsigned, f);
    u += 0x7FFFu + ((u >> 16) & 1u);
    return (unsigned short)(u >> 16);
}
__device__ __forceinline__ float bf2f(unsigned short h) {
    unsigned u = ((unsigned)h) << 16;
    return __builtin_bit_cast(float, u);
}

// ---------------------------------------------------------------------------
// One prep kernel: edge weights (2 layers) + node weights -> bf16 hi/lo.
__global__ __launch_bounds__(256) void prep_all(
    const float* __restrict__ e00, const float* __restrict__ e01, const float* __restrict__ e02,
    const float* __restrict__ e10, const float* __restrict__ e11, const float* __restrict__ e12,
    const float* __restrict__ n0n, const float* __restrict__ n0r,
    const float* __restrict__ n1n, const float* __restrict__ n1r,
    unsigned short* __restrict__ ewb, unsigned short* __restrict__ nwb, int do_node)
{
    int idx = blockIdx.x * 256 + threadIdx.x;   // grid 2624 -> 671744 exact
    float v; unsigned short *ph, *pl; int off;
    if (idx < 262144) {
        int l = idx >> 17;
        int t = idx & 131071;
        unsigned short* blk = ewb + (size_t)l * 262144;
        const float* w0 = l ? e10 : e00;
        const float* w1 = l ? e11 : e01;
        const float* w2 = l ? e12 : e02;
        if (t < 81920) {
            int n = t / 320, k = t - n * 320;
            v = (k < 300) ? w0[n * 300 + k] : 0.f;
            ph = blk; pl = blk + 81920; off = t;
        } else if (t < 114688) {
            int r = t - 81920; v = w1[r];
            ph = blk + 163840; pl = blk + 196608; off = r;
        } else {
            int r = t - 114688; v = w2[r];
            ph = blk + 229376; pl = blk + 245760; off = r;
        }
    } else {
        if (!do_node) return;
        int t = idx - 262144;                    // 0 .. 409599
        int l = t / 204800;
        int r = t - l * 204800;
        int mat = r / 102400;
        int q = r - mat * 102400;
        int n = q / 320, k = q - n * 320;
        const float* src = l ? (mat ? n1r : n1n) : (mat ? n0r : n0n);
        v = (n < 300 && k < 300) ? src[n * 300 + k] : 0.f;
        unsigned short* blk = nwb + (size_t)l * 409600;
        ph = blk + mat * 204800; pl = ph + 102400; off = q;
    }
    unsigned short hb = f2bf(v);
    ph[off] = hb; pl[off] = f2bf(v - bf2f(hb));
}

// ---------------------------------------------------------------------------
// 4-lane-group transpose (by value; verified rounds 6-8).
__device__ __forceinline__ short8v mk_frag(uint2 tlo, uint2 thi,
                                           int s1, int s2, bool hif)
{
    unsigned a0 = (unsigned)__shfl((int)tlo.x, s1);
    unsigned b0 = (unsigned)__shfl((int)thi.x, s1);
    unsigned a1 = (unsigned)__shfl((int)tlo.y, s1);
    unsigned b1 = (unsigned)__shfl((int)thi.y, s1);
    unsigned a2 = (unsigned)__shfl((int)tlo.x, s2);
    unsigned b2 = (unsigned)__shfl((int)thi.x, s2);
    unsigned a3 = (unsigned)__shfl((int)tlo.y, s2);
    unsigned b3 = (unsigned)__shfl((int)thi.y, s2);
    union { unsigned u[4]; short8v v; } r;
    r.u[0] = hif ? b0 : a0; r.u[1] = hif ? b1 : a1;
    r.u[2] = hif ? b2 : a2; r.u[3] = hif ? b3 : a3;
    return r.v;
}

// ---------------------------------------------------------------------------
// Edge MLP: 4 waves x 16 pairs; weights staged per-k-chunk into LDS dbuf via
// global_load_lds (shared by all 4 waves -> L2 weight traffic /4), tile-major
// slot layout: slot == lane -> linear LDS dest (HW requirement) AND
// conflict-free ds_read_b128 (each lane its own 16B).
__global__ __launch_bounds__(256, 2) void edge_mfma(
    const float* __restrict__ x,
    const unsigned short* __restrict__ w0h, const unsigned short* __restrict__ w0l,
    const unsigned short* __restrict__ w1h, const unsigned short* __restrict__ w1l,
    const unsigned short* __restrict__ w2h, const unsigned short* __restrict__ w2l,
    const float* __restrict__ wo, const float* __restrict__ bo,
    float* __restrict__ adjraw)
{
    // [sel][hi: 0..8191 | lo: 8192..16383] ushorts; 2 x 32 KB = 64 KB
    __shared__ __align__(16) unsigned short ldsW[2][16384];

    const int tid  = threadIdx.x;
    const int lane = tid & 63;
    const int w    = tid >> 6;
    const int l15  = lane & 15;
    const int l4   = lane >> 4;

    // this lane-column's pair
    const int p = blockIdx.x * 64 + w * 16 + l15;
    int bb = p / NPAIRS;
    int u  = p - bb * NPAIRS;
    int ii = 0;
    while (u >= N_ - ii) { u -= N_ - ii; ++ii; }
    int jj = ii + u;
    const float* xi = x + ((size_t)bb * N_ + ii) * D_;
    const float* xj = x + ((size_t)bb * N_ + jj) * D_;

    const int s1 = (lane & 15) | ((lane & 16) << 1);
    const int s2 = s1 + 16;
    const bool hif = (l4 >> 1) != 0;

    // staging: per issue, wave w covers one tile (64 slots = 64 lanes);
    // lane's global row = tile*16 + l15, 16B piece = l4. LDS dest = linear.
    auto stage_g1 = [&](int c, int sel) {
        #pragma unroll
        for (int i = 0; i < 4; ++i) {
            const int tile = i * 4 + w;
            const size_t g = (size_t)(tile * 16 + l15) * 320 + c * 32 + l4 * 8;
            __builtin_amdgcn_global_load_lds((const unsigned int*)(w0h + g),
                (unsigned int*)(&ldsW[sel][tile * 512]), 16, 0, 0);
            __builtin_amdgcn_global_load_lds((const unsigned int*)(w0l + g),
                (unsigned int*)(&ldsW[sel][8192 + tile * 512]), 16, 0, 0);
        }
    };
    auto stage_g2 = [&](int c, int sel) {
        #pragma unroll
        for (int i = 0; i < 2; ++i) {
            const int tile = i * 4 + w;
            const size_t g = (size_t)(tile * 16 + l15) * 256 + c * 32 + l4 * 8;
            __builtin_amdgcn_global_load_lds((const unsigned int*)(w1h + g),
                (unsigned int*)(&ldsW[sel][tile * 512]), 16, 0, 0);
            __builtin_amdgcn_global_load_lds((const unsigned int*)(w1l + g),
                (unsigned int*)(&ldsW[sel][8192 + tile * 512]), 16, 0, 0);
        }
    };
    auto stage_g3 = [&](int c, int sel) {
        #pragma unroll
        for (int i = 0; i < 2; ++i) {
            const int tile = i * 4 + w;
            const size_t g = (size_t)(tile * 16 + l15) * 128 + c * 32 + l4 * 8;
            __builtin_amdgcn_global_load_lds((const unsigned int*)(w2h + g),
                (unsigned int*)(&ldsW[sel][tile * 512]), 16, 0, 0);
            __builtin_amdgcn_global_load_lds((const unsigned int*)(w2l + g),
                (unsigned int*)(&ldsW[sel][8192 + tile * 512]), 16, 0, 0);
        }
    };

    // ---------------- G1: h0 = w0 @ xij^T, K=320 (10 chunks) ----------------
    f32x4 acc[16];
    #pragma unroll
    for (int t = 0; t < 16; ++t) acc[t] = (f32x4){0.f, 0.f, 0.f, 0.f};

    stage_g1(0, 0);
    __syncthreads();   // implicit vmcnt(0) drain -> buf0 ready

    #pragma unroll 1
    for (int c = 0; c < 10; ++c) {
        const int sel = c & 1;
        if (c < 9) stage_g1(c + 1, sel ^ 1);
        else       stage_g2(0, sel ^ 1);          // pre-stage G2 chunk 0

        // activation fragment for chunk c (overlaps staging latency)
        const int d0 = c * 32 + l4 * 8;
        float v[8];
        if (c < 9) {
            float4 a0 = *(const float4*)(xi + d0);
            float4 a1 = *(const float4*)(xi + d0 + 4);
            float4 b0 = *(const float4*)(xj + d0);
            float4 b1 = *(const float4*)(xj + d0 + 4);
            #pragma unroll
            for (int e = 0; e < 4; ++e) {
                v[e]     = expf(-fabsf((&a0.x)[e] - (&b0.x)[e]));
                v[4 + e] = expf(-fabsf((&a1.x)[e] - (&b1.x)[e]));
            }
        } else {
            #pragma unroll
            for (int e = 0; e < 8; ++e) {
                int d = d0 + e;
                v[e] = (d < D_) ? expf(-fabsf(xi[d] - xj[d])) : 0.f;
            }
        }
        short8v bh, bl;
        #pragma unroll
        for (int e = 0; e < 8; ++e) {
            unsigned short hb = f2bf(v[e]);
            bh[e] = (short)hb;
            bl[e] = (short)f2bf(v[e] - bf2f(hb));
        }

        #pragma unroll
        for (int t = 0; t < 16; ++t) {
            short8v wh = *(const short8v*)(&ldsW[sel][t * 512 + lane * 8]);
            short8v wl = *(const short8v*)(&ldsW[sel][8192 + t * 512 + lane * 8]);
            acc[t] = __builtin_amdgcn_mfma_f32_16x16x32_bf16(wh, bh, acc[t], 0, 0, 0);
            acc[t] = __builtin_amdgcn_mfma_f32_16x16x32_bf16(wh, bl, acc[t], 0, 0, 0);
            acc[t] = __builtin_amdgcn_mfma_f32_16x16x32_bf16(wl, bh, acc[t], 0, 0, 0);
        }
        __syncthreads();   // drains staging (vmcnt0) + all reads of sel done
    }

    // pack h0 -> bf16 hi/lo
    uint2 hh[16], ll[16];
    #pragma unroll
    for (int t = 0; t < 16; ++t) {
        unsigned short h_[4], l_[4];
        #pragma unroll
        for (int r = 0; r < 4; ++r) {
            float f = lrelu(acc[t][r]);
            h_[r] = f2bf(f);
            l_[r] = f2bf(f - bf2f(h_[r]));
        }
        hh[t].x = (unsigned)h_[0] | ((unsigned)h_[1] << 16);
        hh[t].y = (unsigned)h_[2] | ((unsigned)h_[3] << 16);
        ll[t].x = (unsigned)l_[0] | ((unsigned)l_[1] << 16);
        ll[t].y = (unsigned)l_[2] | ((unsigned)l_[3] << 16);
    }

    // ---------------- G2: h1 = w1 @ h0^T, K=256 (8 chunks) ----------------
    f32x4 acc2[8];
    #pragma unroll
    for (int t = 0; t < 8; ++t) acc2[t] = (f32x4){0.f, 0.f, 0.f, 0.f};

    #pragma unroll 1
    for (int ks = 0; ks < 8; ++ks) {
        const int sel = ks & 1;
        if (ks < 7) stage_g2(ks + 1, sel ^ 1);
        else        stage_g3(0, sel ^ 1);         // pre-stage G3 chunk 0

        short8v bh = mk_frag(hh[2 * ks], hh[2 * ks + 1], s1, s2, hif);
        short8v bl = mk_frag(ll[2 * ks], ll[2 * ks + 1], s1, s2, hif);

        #pragma unroll
        for (int t = 0; t < 8; ++t) {
            short8v wh = *(const short8v*)(&ldsW[sel][t * 512 + lane * 8]);
            short8v wl = *(const short8v*)(&ldsW[sel][8192 + t * 512 + lane * 8]);
            acc2[t] = __builtin_amdgcn_mfma_f32_16x16x32_bf16(wh, bh, acc2[t], 0, 0, 0);
            acc2[t] = __builtin_amdgcn_mfma_f32_16x16x32_bf16(wh, bl, acc2[t], 0, 0, 0);
            acc2[t] = __builtin_amdgcn_mfma_f32_16x16x32_bf16(wl, bh, acc2[t], 0, 0, 0);
        }
        __syncthreads();
    }

    // pack h1
    uint2 hh1[8], ll1[8];
    #pragma unroll
    for (int t = 0; t < 8; ++t) {
        unsigned short h_[4], l_[4];
        #pragma unroll
        for (int r = 0; r < 4; ++r) {
            float f = lrelu(acc2[t][r]);
            h_[r] = f2bf(f);
            l_[r] = f2bf(f - bf2f(h_[r]));
        }
        hh1[t].x = (unsigned)h_[0] | ((unsigned)h_[1] << 16);
        hh1[t].y = (unsigned)h_[2] | ((unsigned)h_[3] << 16);
        ll1[t].x = (unsigned)l_[0] | ((unsigned)l_[1] << 16);
        ll1[t].y = (unsigned)l_[2] | ((unsigned)l_[3] << 16);
    }

    // ---------------- G3: h2 = w2 @ h1^T, K=128 (4 chunks) ----------------
    f32x4 acc3[8];
    #pragma unroll
    for (int t = 0; t < 8; ++t) acc3[t] = (f32x4){0.f, 0.f, 0.f, 0.f};

    #pragma unroll 1
    for (int ks = 0; ks < 4; ++ks) {
        const int sel = ks & 1;
        if (ks < 3) stage_g3(ks + 1, sel ^ 1);

        short8v bh = mk_frag(hh1[2 * ks], hh1[2 * ks + 1], s1, s2, hif);
        short8v bl = mk_frag(ll1[2 * ks], ll1[2 * ks + 1], s1, s2, hif);

        #pragma unroll
        for (int t = 0; t < 8; ++t) {
            short8v wh = *(const short8v*)(&ldsW[sel][t * 512 + lane * 8]);
            short8v wl = *(const short8v*)(&ldsW[sel][8192 + t * 512 + lane * 8]);
            acc3[t] = __builtin_amdgcn_mfma_f32_16x16x32_bf16(wh, bh, acc3[t], 0, 0, 0);
            acc3[t] = __builtin_amdgcn_mfma_f32_16x16x32_bf16(wh, bl, acc3[t], 0, 0, 0);
            acc3[t] = __builtin_amdgcn_mfma_f32_16x16x32_bf16(wl, bh, acc3[t], 0, 0, 0);
        }
        __syncthreads();
    }

    // ---------------- sim: in-register reduce over 128 channels ------------
    float ps = 0.f;
    #pragma unroll
    for (int t = 0; t < 8; ++t) {
        float4 wov = *(const float4*)(wo + t * 16 + l4 * 4);
        #pragma unroll
        for (int r = 0; r < 4; ++r)
            ps += lrelu(acc3[t][r]) * (&wov.x)[r];
    }
    ps += __shfl_xor(ps, 16);
    ps += __shfl_xor(ps, 32);
    if (l4 == 0) {
        float a = 1.f / (1.f + expf(-(ps + bo[0])));
        if (ii == jj) a = 0.f;
        adjraw[(size_t)bb * 441 + ii * 21 + jj] = a;
        adjraw[(size_t)bb * 441 + jj * 21 + ii] = a;
    }
}

// ---------------------------------------------------------------------------
// top-5 per row (fallback path only)
__global__ __launch_bounds__(64) void topk_kernel(
    const float* __restrict__ adjraw, float* __restrict__ A)
{
    const int row = blockIdx.x;
    const int lane = threadIdx.x;
    __shared__ float sadj[32];
    __shared__ unsigned s_used;
    if (lane < N_) sadj[lane] = adjraw[row * N_ + lane];
    __syncthreads();
    if (lane == 0) {
        unsigned used = 0;
        for (int r = 0; r < 5; ++r) {
            float best = -1.f; int bi = 0;
            for (int j = 0; j < N_; ++j) {
                if (used & (1u << j)) continue;
                if (sadj[j] > best) { best = sadj[j]; bi = j; }
            }
            used |= (1u << bi);
        }
        s_used = used;
    }
    __syncthreads();
    if (lane < N_)
        A[row * N_ + lane] = ((s_used >> lane) & 1u) ? sadj[lane] : 0.f;
}

// ---------------------------------------------------------------------------
// Node GEMM via MFMA: P = x@wn^T and R = x@wr^T, M=2688 rows.
__global__ __launch_bounds__(256, 4) void node_gemm(
    const float* __restrict__ xin,
    const unsigned short* __restrict__ wnh, const unsigned short* __restrict__ wnl,
    const unsigned short* __restrict__ wrh, const unsigned short* __restrict__ wrl,
    float* __restrict__ nbuf)
{
    __shared__ __align__(16) unsigned short sxh[2][512], sxl[2][512];

    const int tid  = threadIdx.x;
    const int lane = tid & 63;
    const int w    = tid >> 6;
    const int l15  = lane & 15;
    const int l4   = lane >> 4;
    const int M0   = blockIdx.x * 16;
    const int mat  = blockIdx.y;

    const unsigned short* ah_base = mat ? wrh : wnh;
    const unsigned short* al_base = mat ? wrl : wnl;
    float* ob = nbuf + (size_t)mat * NROWS * DP;

    const int sm = tid >> 4;
    const int sk = (tid & 15) * 2;
    const float* xrow = xin + (size_t)(M0 + sm) * D_;
    const int sa = sm * 32 + (((sk >> 3) ^ ((sm >> 1) & 3)) << 3) + (sk & 7);
    const int xr_off = l15 * 32 + ((l4 ^ ((l15 >> 1) & 3)) << 3);

    f32x4 acc[5];
    #pragma unroll
    for (int t = 0; t < 5; ++t) acc[t] = (f32x4){0.f, 0.f, 0.f, 0.f};

    {
        float2 v = *(const float2*)(xrow + sk);
        unsigned short h0 = f2bf(v.x), h1 = f2bf(v.y);
        unsigned uh = (unsigned)h0 | ((unsigned)h1 << 16);
        unsigned ul = (unsigned)f2bf(v.x - bf2f(h0)) |
                      ((unsigned)f2bf(v.y - bf2f(h1)) << 16);
        *(unsigned*)(&sxh[0][sa]) = uh;
        *(unsigned*)(&sxl[0][sa]) = ul;
    }
    __syncthreads();

    #pragma unroll 1
    for (int c = 0; c < 10; ++c) {
        const int sel = c & 1;
        short8v wh[5], wl[5];
        const int kg = c * 32 + l4 * 8;
        #pragma unroll
        for (int t = 0; t < 5; ++t) {
            const size_t n = (size_t)((w * 5 + t) * 16 + l15);
            wh[t] = *(const short8v*)(ah_base + n * DP + kg);
            wl[t] = *(const short8v*)(al_base + n * DP + kg);
        }
        float2 xv; bool have = false;
        if (c < 9) {
            const int k0 = (c + 1) * 32 + sk;
            if (k0 < D_) { xv = *(const float2*)(xrow + k0); have = true; }
        }
        short8v bh = *(const short8v*)(sxh[sel] + xr_off);
        short8v bl = *(const short8v*)(sxl[sel] + xr_off);
        #pragma unroll
        for (int t = 0; t < 5; ++t) {
            acc[t] = __builtin_amdgcn_mfma_f32_16x16x32_bf16(wh[t], bh, acc[t], 0, 0, 0);
            acc[t] = __builtin_amdgcn_mfma_f32_16x16x32_bf16(wh[t], bl, acc[t], 0, 0, 0);
            acc[t] = __builtin_amdgcn_mfma_f32_16x16x32_bf16(wl[t], bh, acc[t], 0, 0, 0);
        }
        if (c < 9) {
            unsigned uh = 0, ul = 0;
            if (have) {
                unsigned short h0 = f2bf(xv.x), h1 = f2bf(xv.y);
                uh = (unsigned)h0 | ((unsigned)h1 << 16);
                ul = (unsigned)f2bf(xv.x - bf2f(h0)) |
                     ((unsigned)f2bf(xv.y - bf2f(h1)) << 16);
            }
            *(unsigned*)(&sxh[sel ^ 1][sa]) = uh;
            *(unsigned*)(&sxl[sel ^ 1][sa]) = ul;
        }
        __syncthreads();
    }

    #pragma unroll
    for (int t = 0; t < 5; ++t) {
        const int n0 = (w * 5 + t) * 16 + l4 * 4;
        float4 v;
        v.x = acc[t][0]; v.y = acc[t][1]; v.z = acc[t][2]; v.w = acc[t][3];
        *(float4*)(ob + (size_t)(M0 + l15) * DP + n0) = v;
    }
}

// ---------------------------------------------------------------------------
// Fused top-k + combine: out = lrelu((A@P + rs*(bn+e0))*0.2 + R + br)
__global__ __launch_bounds__(256) void node_combine(
    const float* __restrict__ adjraw, const float* __restrict__ nbuf,
    const float* __restrict__ bn, const float* __restrict__ br,
    const float* __restrict__ eemb, float* __restrict__ out)
{
    const int row = blockIdx.x;           // 0..2687
    const int b = row / N_;
    const int tid = threadIdx.x;
    __shared__ float sadj[24];
    __shared__ float sA[24];
    __shared__ float s_rs;
    if (tid < N_) sadj[tid] = adjraw[(size_t)row * N_ + tid];
    __syncthreads();
    if (tid == 0) {
        unsigned used = 0;
        for (int r = 0; r < 5; ++r) {
            float best = -1.f; int bi = 0;
            for (int j = 0; j < N_; ++j) {
                if (used & (1u << j)) continue;
                if (sadj[j] > best) { best = sadj[j]; bi = j; }
            }
            used |= (1u << bi);
        }
        float rs = 0.f;
        for (int j = 0; j < N_; ++j) {
            float m = ((used >> j) & 1u) ? sadj[j] : 0.f;
            sA[j] = m; rs += m;
        }
        s_rs = rs;
    }
    __syncthreads();
    const float* Pb = nbuf + (size_t)b * N_ * DP;
    const float* Rr = nbuf + (size_t)NROWS * DP + (size_t)row * DP;
    const float rs = s_rs;
    #pragma unroll
    for (int pass = 0; pass < 2; ++pass) {
        int o = tid + pass * 256;
        if (o < D_) {
            float m = 0.f;
            #pragma unroll
            for (int s = 0; s < N_; ++s) m += sA[s] * Pb[(size_t)s * DP + o];
            out[(size_t)row * D_ + o] =
                lrelu((m + rs * (bn[o] + eemb[o])) * 0.2f + Rr[o] + br[o]);
        }
    }
}

// ---------------------------------------------------------------------------
// Fallback fp32 node kernel (if ws too small for nbuf)
__global__ __launch_bounds__(320) void node_kernel(
    const float* __restrict__ xin, const float* __restrict__ A,
    const float* __restrict__ wn, const float* __restrict__ bn,
    const float* __restrict__ wr, const float* __restrict__ br,
    const float* __restrict__ eemb, float* __restrict__ out)
{
    const int b = blockIdx.x;
    const int tid = threadIdx.x;
    __shared__ float sx[N_][304];
    __shared__ float sA[N_][24];
    __shared__ float srs[N_];

    const float* xb = xin + (size_t)b * N_ * D_;
    for (int it = tid; it < N_ * D_; it += 320) {
        int j = it / D_, d = it - (it / D_) * D_;
        sx[j][d] = xb[it];
    }
    for (int it = tid; it < N_ * N_; it += 320) {
        int t = it / N_, s = it - (it / N_) * N_;
        sA[t][s] = A[((size_t)b * N_ + t) * N_ + s];
    }
    __syncthreads();
    if (tid < N_) {
        float s = 0.f;
        #pragma unroll
        for (int j = 0; j < N_; ++j) s += sA[tid][j];
        srs[tid] = s;
    }
    __syncthreads();

    const int o = tid;
    if (o < D_) {
        float nacc[N_], racc[N_];
        #pragma unroll
        for (int j = 0; j < N_; ++j) { nacc[j] = 0.f; racc[j] = 0.f; }
        const float* wnr = wn + (size_t)o * D_;
        const float* wrr = wr + (size_t)o * D_;
        for (int k4 = 0; k4 < D_; k4 += 4) {
            float4 wn4 = *(const float4*)(wnr + k4);
            float4 wr4 = *(const float4*)(wrr + k4);
            #pragma unroll
            for (int j = 0; j < N_; ++j) {
                float4 xv = *(const float4*)(&sx[j][k4]);
                nacc[j] += wn4.x * xv.x; nacc[j] += wn4.y * xv.y;
                nacc[j] += wn4.z * xv.z; nacc[j] += wn4.w * xv.w;
                racc[j] += wr4.x * xv.x; racc[j] += wr4.y * xv.y;
                racc[j] += wr4.z * xv.z; racc[j] += wr4.w * xv.w;
            }
        }
        const float bn_o = bn[o], br_o = br[o], e0_o = eemb[o];
        const float add_o = bn_o + e0_o;
        #pragma unroll
        for (int t = 0; t < N_; ++t) {
            float m = 0.f;
            #pragma unroll
            for (int s = 0; s < N_; ++s) m += sA[t][s] * nacc[s];
            out[((size_t)b * N_ + t) * D_ + o] =
                lrelu((m + srs[t] * add_o) * 0.2f + racc[t] + br_o);
        }
    }
}

// ---------------------------------------------------------------------------
extern "C" void kernel_launch(void* const* d_in, const int* in_sizes, int n_in,
                              void* d_out, int out_size, void* d_ws, size_t ws_size,
                              hipStream_t stream)
{
    const float* x0 = (const float*)d_in[0];
    auto L = [&](int l, int k) { return (const float*)d_in[1 + l * 10 + k]; };

    // ws layout:
    //   adjraw @0        (225,792)
    //   A      @256KB    (225,792)               (fallback only)
    //   edge w @512KB    (2 x 512KB)             -> ends 1,572,864
    //   node w @1.5MB    (2 x 819,200)           -> ends 3,211,264
    //   nbuf   @3,211,264 (6,881,280)            -> ends 10,092,544
    float* adjraw = (float*)d_ws;
    float* A      = (float*)((char*)d_ws + 262144);
    unsigned short* ewb = (unsigned short*)((char*)d_ws + 524288);
    unsigned short* nwb = (unsigned short*)((char*)d_ws + 1572864);
    float* nbuf   = (float*)((char*)d_ws + 3211264);
    const size_t WS_NEED = 10092544;
    const bool newnode = (ws_size >= WS_NEED);

    prep_all<<<2624, 256, 0, stream>>>(
        L(0,0), L(0,1), L(0,2), L(1,0), L(1,1), L(1,2),
        L(0,5), L(0,7), L(1,5), L(1,7), ewb, nwb, newnode ? 1 : 0);

    for (int l = 0; l < 2; ++l) {
        const float* xin = (l == 0) ? x0 : (const float*)d_out;
        unsigned short* blk = ewb + (size_t)l * 262144;
        edge_mfma<<<GRID_E, 256, 0, stream>>>(xin,
            blk, blk + 81920, blk + 163840, blk + 196608, blk + 229376, blk + 245760,
            L(l, 3), L(l, 4), adjraw);
        if (newnode) {
            unsigned short* nblk = nwb + (size_t)l * 409600;
            node_gemm<<<dim3(NROWS / 16, 2), 256, 0, stream>>>(
                xin, nblk, nblk + 102400, nblk + 204800, nblk + 307200, nbuf);
            node_combine<<<NROWS, 256, 0, stream>>>(adjraw, nbuf, L(l, 6), L(l, 8),
                                                    L(l, 9), (float*)d_out);
        } else {
            topk_kernel<<<NROWS, 64, 0, stream>>>(adjraw, A);
            node_kernel<<<B_, 320, 0, stream>>>(xin, A, L(l, 5), L(l, 6), L(l, 7),
                                                L(l, 8), L(l, 9), (float*)d_out);
        }
    }
}

// Round 10
// 177.491 us; speedup vs baseline: 1.9268x; 1.1857x over previous
//
#include <hip/hip_runtime.h>
#include <math.h>

#define B_  128
#define N_  21
#define D_  300
#define NPAIRS 231                  // upper-tri incl diag
#define NPAIR_TOT (B_ * NPAIRS)     // 29568
#define GRID_E (NPAIR_TOT / 64)     // 462 blocks x 4 waves x 16 pairs
#define NROWS (B_ * N_)             // 2688
#define DP  320

typedef __attribute__((ext_vector_type(8))) short short8v;
typedef __attribute__((ext_vector_type(4))) float f32x4;

__device__ __forceinline__ float lrelu(float v) { return v > 0.f ? v : 0.01f * v; }

__device__ __forceinline__ unsigned short f2bf(float f) {
    unsigned u = __builtin_bit_cast(unsigned, f);
    u += 0x7FFFu + ((u >> 16) & 1u);
    return (unsigned short)(u >> 16);
}
__device__ __forceinline__ float bf2f(unsigned short h) {
    unsigned u = ((unsigned)h) << 16;
    return __builtin_bit_cast(float, u);
}

// ---------------------------------------------------------------------------
// One prep kernel: edge weights (2 layers) + node weights -> bf16 hi/lo.
__global__ __launch_bounds__(256) void prep_all(
    const float* __restrict__ e00, const float* __restrict__ e01, const float* __restrict__ e02,
    const float* __restrict__ e10, const float* __restrict__ e11, const float* __restrict__ e12,
    const float* __restrict__ n0n, const float* __restrict__ n0r,
    const float* __restrict__ n1n, const float* __restrict__ n1r,
    unsigned short* __restrict__ ewb, unsigned short* __restrict__ nwb, int do_node)
{
    int idx = blockIdx.x * 256 + threadIdx.x;   // grid 2624 -> 671744 exact
    float v; unsigned short *ph, *pl; int off;
    if (idx < 262144) {
        int l = idx >> 17;
        int t = idx & 131071;
        unsigned short* blk = ewb + (size_t)l * 262144;
        const float* w0 = l ? e10 : e00;
        const float* w1 = l ? e11 : e01;
        const float* w2 = l ? e12 : e02;
        if (t < 81920) {
            int n = t / 320, k = t - n * 320;
            v = (k < 300) ? w0[n * 300 + k] : 0.f;
            ph = blk; pl = blk + 81920; off = t;
        } else if (t < 114688) {
            int r = t - 81920; v = w1[r];
            ph = blk + 163840; pl = blk + 196608; off = r;
        } else {
            int r = t - 114688; v = w2[r];
            ph = blk + 229376; pl = blk + 245760; off = r;
        }
    } else {
        if (!do_node) return;
        int t = idx - 262144;                    // 0 .. 409599
        int l = t / 204800;
        int r = t - l * 204800;
        int mat = r / 102400;
        int q = r - mat * 102400;
        int n = q / 320, k = q - n * 320;
        const float* src = l ? (mat ? n1r : n1n) : (mat ? n0r : n0n);
        v = (n < 300 && k < 300) ? src[n * 300 + k] : 0.f;
        unsigned short* blk = nwb + (size_t)l * 409600;
        ph = blk + mat * 204800; pl = ph + 102400; off = q;
    }
    unsigned short hb = f2bf(v);
    ph[off] = hb; pl[off] = f2bf(v - bf2f(hb));
}

// ---------------------------------------------------------------------------
// 4-lane-group transpose (by value; verified rounds 6-9).
__device__ __forceinline__ short8v mk_frag(uint2 tlo, uint2 thi,
                                           int s1, int s2, bool hif)
{
    unsigned a0 = (unsigned)__shfl((int)tlo.x, s1);
    unsigned b0 = (unsigned)__shfl((int)thi.x, s1);
    unsigned a1 = (unsigned)__shfl((int)tlo.y, s1);
    unsigned b1 = (unsigned)__shfl((int)thi.y, s1);
    unsigned a2 = (unsigned)__shfl((int)tlo.x, s2);
    unsigned b2 = (unsigned)__shfl((int)thi.x, s2);
    unsigned a3 = (unsigned)__shfl((int)tlo.y, s2);
    unsigned b3 = (unsigned)__shfl((int)thi.y, s2);
    union { unsigned u[4]; short8v v; } r;
    r.u[0] = hif ? b0 : a0; r.u[1] = hif ? b1 : a1;
    r.u[2] = hif ? b2 : a2; r.u[3] = hif ? b3 : a3;
    return r.v;
}

// ---------------------------------------------------------------------------
// Edge MLP: 4 waves x 16 pairs; weights staged per-k-chunk into LDS dbuf via
// global_load_lds (shared across waves), tile-major slot layout (linear dest,
// conflict-free b128 reads). G2/G3 chunk loops FULLY UNROLLED so the packed
// h0/h1 register arrays are statically indexed (rule #20: no scratch).
__global__ __launch_bounds__(256, 2) void edge_mfma(
    const float* __restrict__ x,
    const unsigned short* __restrict__ w0h, const unsigned short* __restrict__ w0l,
    const unsigned short* __restrict__ w1h, const unsigned short* __restrict__ w1l,
    const unsigned short* __restrict__ w2h, const unsigned short* __restrict__ w2l,
    const float* __restrict__ wo, const float* __restrict__ bo,
    float* __restrict__ adjraw)
{
    // [sel][hi: 0..8191 | lo: 8192..16383] ushorts; 2 x 32 KB = 64 KB
    __shared__ __align__(16) unsigned short ldsW[2][16384];

    const int tid  = threadIdx.x;
    const int lane = tid & 63;
    const int w    = tid >> 6;
    const int l15  = lane & 15;
    const int l4   = lane >> 4;

    // this lane-column's pair
    const int p = blockIdx.x * 64 + w * 16 + l15;
    int bb = p / NPAIRS;
    int u  = p - bb * NPAIRS;
    int ii = 0;
    while (u >= N_ - ii) { u -= N_ - ii; ++ii; }
    int jj = ii + u;
    const float* xi = x + ((size_t)bb * N_ + ii) * D_;
    const float* xj = x + ((size_t)bb * N_ + jj) * D_;

    const int s1 = (lane & 15) | ((lane & 16) << 1);
    const int s2 = s1 + 16;
    const bool hif = (l4 >> 1) != 0;

    auto stage_g1 = [&](int c, int sel) {
        #pragma unroll
        for (int i = 0; i < 4; ++i) {
            const int tile = i * 4 + w;
            const size_t g = (size_t)(tile * 16 + l15) * 320 + c * 32 + l4 * 8;
            __builtin_amdgcn_global_load_lds((const unsigned int*)(w0h + g),
                (unsigned int*)(&ldsW[sel][tile * 512]), 16, 0, 0);
            __builtin_amdgcn_global_load_lds((const unsigned int*)(w0l + g),
                (unsigned int*)(&ldsW[sel][8192 + tile * 512]), 16, 0, 0);
        }
    };
    auto stage_g2 = [&](int c, int sel) {
        #pragma unroll
        for (int i = 0; i < 2; ++i) {
            const int tile = i * 4 + w;
            const size_t g = (size_t)(tile * 16 + l15) * 256 + c * 32 + l4 * 8;
            __builtin_amdgcn_global_load_lds((const unsigned int*)(w1h + g),
                (unsigned int*)(&ldsW[sel][tile * 512]), 16, 0, 0);
            __builtin_amdgcn_global_load_lds((const unsigned int*)(w1l + g),
                (unsigned int*)(&ldsW[sel][8192 + tile * 512]), 16, 0, 0);
        }
    };
    auto stage_g3 = [&](int c, int sel) {
        #pragma unroll
        for (int i = 0; i < 2; ++i) {
            const int tile = i * 4 + w;
            const size_t g = (size_t)(tile * 16 + l15) * 128 + c * 32 + l4 * 8;
            __builtin_amdgcn_global_load_lds((const unsigned int*)(w2h + g),
                (unsigned int*)(&ldsW[sel][tile * 512]), 16, 0, 0);
            __builtin_amdgcn_global_load_lds((const unsigned int*)(w2l + g),
                (unsigned int*)(&ldsW[sel][8192 + tile * 512]), 16, 0, 0);
        }
    };

    // ---------------- G1: h0 = w0 @ xij^T, K=320 (10 chunks) ----------------
    f32x4 acc[16];
    #pragma unroll
    for (int t = 0; t < 16; ++t) acc[t] = (f32x4){0.f, 0.f, 0.f, 0.f};

    stage_g1(0, 0);
    __syncthreads();   // implicit vmcnt(0) drain -> buf0 ready

    #pragma unroll 1
    for (int c = 0; c < 10; ++c) {
        const int sel = c & 1;
        if (c < 9) stage_g1(c + 1, sel ^ 1);
        else       stage_g2(0, sel ^ 1);          // pre-stage G2 chunk 0

        // activation fragment for chunk c (overlaps staging latency)
        const int d0 = c * 32 + l4 * 8;
        float v[8];
        if (c < 9) {
            float4 a0 = *(const float4*)(xi + d0);
            float4 a1 = *(const float4*)(xi + d0 + 4);
            float4 b0 = *(const float4*)(xj + d0);
            float4 b1 = *(const float4*)(xj + d0 + 4);
            #pragma unroll
            for (int e = 0; e < 4; ++e) {
                v[e]     = expf(-fabsf((&a0.x)[e] - (&b0.x)[e]));
                v[4 + e] = expf(-fabsf((&a1.x)[e] - (&b1.x)[e]));
            }
        } else {
            #pragma unroll
            for (int e = 0; e < 8; ++e) {
                int d = d0 + e;
                v[e] = (d < D_) ? expf(-fabsf(xi[d] - xj[d])) : 0.f;
            }
        }
        short8v bh, bl;
        #pragma unroll
        for (int e = 0; e < 8; ++e) {
            unsigned short hb = f2bf(v[e]);
            bh[e] = (short)hb;
            bl[e] = (short)f2bf(v[e] - bf2f(hb));
        }

        #pragma unroll
        for (int t = 0; t < 16; ++t) {
            short8v wh = *(const short8v*)(&ldsW[sel][t * 512 + lane * 8]);
            short8v wl = *(const short8v*)(&ldsW[sel][8192 + t * 512 + lane * 8]);
            acc[t] = __builtin_amdgcn_mfma_f32_16x16x32_bf16(wh, bh, acc[t], 0, 0, 0);
            acc[t] = __builtin_amdgcn_mfma_f32_16x16x32_bf16(wh, bl, acc[t], 0, 0, 0);
            acc[t] = __builtin_amdgcn_mfma_f32_16x16x32_bf16(wl, bh, acc[t], 0, 0, 0);
        }
        __syncthreads();   // drains staging (vmcnt0) + all reads of sel done
    }

    // pack h0 -> bf16 hi/lo (static indices throughout)
    uint2 hh[16], ll[16];
    #pragma unroll
    for (int t = 0; t < 16; ++t) {
        unsigned short h_[4], l_[4];
        #pragma unroll
        for (int r = 0; r < 4; ++r) {
            float f = lrelu(acc[t][r]);
            h_[r] = f2bf(f);
            l_[r] = f2bf(f - bf2f(h_[r]));
        }
        hh[t].x = (unsigned)h_[0] | ((unsigned)h_[1] << 16);
        hh[t].y = (unsigned)h_[2] | ((unsigned)h_[3] << 16);
        ll[t].x = (unsigned)l_[0] | ((unsigned)l_[1] << 16);
        ll[t].y = (unsigned)l_[2] | ((unsigned)l_[3] << 16);
    }

    // ---------------- G2: h1 = w1 @ h0^T, K=256 (8 chunks, FULL UNROLL) ----
    f32x4 acc2[8];
    #pragma unroll
    for (int t = 0; t < 8; ++t) acc2[t] = (f32x4){0.f, 0.f, 0.f, 0.f};

    #pragma unroll
    for (int ks = 0; ks < 8; ++ks) {
        const int sel = ks & 1;
        if (ks < 7) stage_g2(ks + 1, sel ^ 1);
        else        stage_g3(0, sel ^ 1);         // pre-stage G3 chunk 0

        short8v bh = mk_frag(hh[2 * ks], hh[2 * ks + 1], s1, s2, hif);
        short8v bl = mk_frag(ll[2 * ks], ll[2 * ks + 1], s1, s2, hif);

        #pragma unroll
        for (int t = 0; t < 8; ++t) {
            short8v wh = *(const short8v*)(&ldsW[sel][t * 512 + lane * 8]);
            short8v wl = *(const short8v*)(&ldsW[sel][8192 + t * 512 + lane * 8]);
            acc2[t] = __builtin_amdgcn_mfma_f32_16x16x32_bf16(wh, bh, acc2[t], 0, 0, 0);
            acc2[t] = __builtin_amdgcn_mfma_f32_16x16x32_bf16(wh, bl, acc2[t], 0, 0, 0);
            acc2[t] = __builtin_amdgcn_mfma_f32_16x16x32_bf16(wl, bh, acc2[t], 0, 0, 0);
        }
        __syncthreads();
    }

    // pack h1
    uint2 hh1[8], ll1[8];
    #pragma unroll
    for (int t = 0; t < 8; ++t) {
        unsigned short h_[4], l_[4];
        #pragma unroll
        for (int r = 0; r < 4; ++r) {
            float f = lrelu(acc2[t][r]);
            h_[r] = f2bf(f);
            l_[r] = f2bf(f - bf2f(h_[r]));
        }
        hh1[t].x = (unsigned)h_[0] | ((unsigned)h_[1] << 16);
        hh1[t].y = (unsigned)h_[2] | ((unsigned)h_[3] << 16);
        ll1[t].x = (unsigned)l_[0] | ((unsigned)l_[1] << 16);
        ll1[t].y = (unsigned)l_[2] | ((unsigned)l_[3] << 16);
    }

    // ---------------- G3: h2 = w2 @ h1^T, K=128 (4 chunks, FULL UNROLL) ----
    f32x4 acc3[8];
    #pragma unroll
    for (int t = 0; t < 8; ++t) acc3[t] = (f32x4){0.f, 0.f, 0.f, 0.f};

    #pragma unroll
    for (int ks = 0; ks < 4; ++ks) {
        const int sel = ks & 1;
        if (ks < 3) stage_g3(ks + 1, sel ^ 1);

        short8v bh = mk_frag(hh1[2 * ks], hh1[2 * ks + 1], s1, s2, hif);
        short8v bl = mk_frag(ll1[2 * ks], ll1[2 * ks + 1], s1, s2, hif);

        #pragma unroll
        for (int t = 0; t < 8; ++t) {
            short8v wh = *(const short8v*)(&ldsW[sel][t * 512 + lane * 8]);
            short8v wl = *(const short8v*)(&ldsW[sel][8192 + t * 512 + lane * 8]);
            acc3[t] = __builtin_amdgcn_mfma_f32_16x16x32_bf16(wh, bh, acc3[t], 0, 0, 0);
            acc3[t] = __builtin_amdgcn_mfma_f32_16x16x32_bf16(wh, bl, acc3[t], 0, 0, 0);
            acc3[t] = __builtin_amdgcn_mfma_f32_16x16x32_bf16(wl, bh, acc3[t], 0, 0, 0);
        }
        __syncthreads();
    }

    // ---------------- sim: in-register reduce over 128 channels ------------
    float ps = 0.f;
    #pragma unroll
    for (int t = 0; t < 8; ++t) {
        float4 wov = *(const float4*)(wo + t * 16 + l4 * 4);
        #pragma unroll
        for (int r = 0; r < 4; ++r)
            ps += lrelu(acc3[t][r]) * (&wov.x)[r];
    }
    ps += __shfl_xor(ps, 16);
    ps += __shfl_xor(ps, 32);
    if (l4 == 0) {
        float a = 1.f / (1.f + expf(-(ps + bo[0])));
        if (ii == jj) a = 0.f;
        adjraw[(size_t)bb * 441 + ii * 21 + jj] = a;
        adjraw[(size_t)bb * 441 + jj * 21 + ii] = a;
    }
}

// ---------------------------------------------------------------------------
// top-5 per row (fallback path only)
__global__ __launch_bounds__(64) void topk_kernel(
    const float* __restrict__ adjraw, float* __restrict__ A)
{
    const int row = blockIdx.x;
    const int lane = threadIdx.x;
    __shared__ float sadj[32];
    __shared__ unsigned s_used;
    if (lane < N_) sadj[lane] = adjraw[row * N_ + lane];
    __syncthreads();
    if (lane == 0) {
        unsigned used = 0;
        for (int r = 0; r < 5; ++r) {
            float best = -1.f; int bi = 0;
            for (int j = 0; j < N_; ++j) {
                if (used & (1u << j)) continue;
                if (sadj[j] > best) { best = sadj[j]; bi = j; }
            }
            used |= (1u << bi);
        }
        s_used = used;
    }
    __syncthreads();
    if (lane < N_)
        A[row * N_ + lane] = ((s_used >> lane) & 1u) ? sadj[lane] : 0.f;
}

// ---------------------------------------------------------------------------
// Node GEMM via MFMA: P = x@wn^T and R = x@wr^T, M=2688 rows.
__global__ __launch_bounds__(256, 4) void node_gemm(
    const float* __restrict__ xin,
    const unsigned short* __restrict__ wnh, const unsigned short* __restrict__ wnl,
    const unsigned short* __restrict__ wrh, const unsigned short* __restrict__ wrl,
    float* __restrict__ nbuf)
{
    __shared__ __align__(16) unsigned short sxh[2][512], sxl[2][512];

    const int tid  = threadIdx.x;
    const int lane = tid & 63;
    const int w    = tid >> 6;
    const int l15  = lane & 15;
    const int l4   = lane >> 4;
    const int M0   = blockIdx.x * 16;
    const int mat  = blockIdx.y;

    const unsigned short* ah_base = mat ? wrh : wnh;
    const unsigned short* al_base = mat ? wrl : wnl;
    float* ob = nbuf + (size_t)mat * NROWS * DP;

    const int sm = tid >> 4;
    const int sk = (tid & 15) * 2;
    const float* xrow = xin + (size_t)(M0 + sm) * D_;
    const int sa = sm * 32 + (((sk >> 3) ^ ((sm >> 1) & 3)) << 3) + (sk & 7);
    const int xr_off = l15 * 32 + ((l4 ^ ((l15 >> 1) & 3)) << 3);

    f32x4 acc[5];
    #pragma unroll
    for (int t = 0; t < 5; ++t) acc[t] = (f32x4){0.f, 0.f, 0.f, 0.f};

    {
        float2 v = *(const float2*)(xrow + sk);
        unsigned short h0 = f2bf(v.x), h1 = f2bf(v.y);
        unsigned uh = (unsigned)h0 | ((unsigned)h1 << 16);
        unsigned ul = (unsigned)f2bf(v.x - bf2f(h0)) |
                      ((unsigned)f2bf(v.y - bf2f(h1)) << 16);
        *(unsigned*)(&sxh[0][sa]) = uh;
        *(unsigned*)(&sxl[0][sa]) = ul;
    }
    __syncthreads();

    #pragma unroll 1
    for (int c = 0; c < 10; ++c) {
        const int sel = c & 1;
        short8v wh[5], wl[5];
        const int kg = c * 32 + l4 * 8;
        #pragma unroll
        for (int t = 0; t < 5; ++t) {
            const size_t n = (size_t)((w * 5 + t) * 16 + l15);
            wh[t] = *(const short8v*)(ah_base + n * DP + kg);
            wl[t] = *(const short8v*)(al_base + n * DP + kg);
        }
        float2 xv; bool have = false;
        if (c < 9) {
            const int k0 = (c + 1) * 32 + sk;
            if (k0 < D_) { xv = *(const float2*)(xrow + k0); have = true; }
        }
        short8v bh = *(const short8v*)(sxh[sel] + xr_off);
        short8v bl = *(const short8v*)(sxl[sel] + xr_off);
        #pragma unroll
        for (int t = 0; t < 5; ++t) {
            acc[t] = __builtin_amdgcn_mfma_f32_16x16x32_bf16(wh[t], bh, acc[t], 0, 0, 0);
            acc[t] = __builtin_amdgcn_mfma_f32_16x16x32_bf16(wh[t], bl, acc[t], 0, 0, 0);
            acc[t] = __builtin_amdgcn_mfma_f32_16x16x32_bf16(wl[t], bh, acc[t], 0, 0, 0);
        }
        if (c < 9) {
            unsigned uh = 0, ul = 0;
            if (have) {
                unsigned short h0 = f2bf(xv.x), h1 = f2bf(xv.y);
                uh = (unsigned)h0 | ((unsigned)h1 << 16);
                ul = (unsigned)f2bf(xv.x - bf2f(h0)) |
                     ((unsigned)f2bf(xv.y - bf2f(h1)) << 16);
            }
            *(unsigned*)(&sxh[sel ^ 1][sa]) = uh;
            *(unsigned*)(&sxl[sel ^ 1][sa]) = ul;
        }
        __syncthreads();
    }

    #pragma unroll
    for (int t = 0; t < 5; ++t) {
        const int n0 = (w * 5 + t) * 16 + l4 * 4;
        float4 v;
        v.x = acc[t][0]; v.y = acc[t][1]; v.z = acc[t][2]; v.w = acc[t][3];
        *(float4*)(ob + (size_t)(M0 + l15) * DP + n0) = v;
    }
}

// ---------------------------------------------------------------------------
// Fused top-k + combine: out = lrelu((A@P + rs*(bn+e0))*0.2 + R + br)
__global__ __launch_bounds__(256) void node_combine(
    const float* __restrict__ adjraw, const float* __restrict__ nbuf,
    const float* __restrict__ bn, const float* __restrict__ br,
    const float* __restrict__ eemb, float* __restrict__ out)
{
    const int row = blockIdx.x;           // 0..2687
    const int b = row / N_;
    const int tid = threadIdx.x;
    __shared__ float sadj[24];
    __shared__ float sA[24];
    __shared__ float s_rs;
    if (tid < N_) sadj[tid] = adjraw[(size_t)row * N_ + tid];
    __syncthreads();
    if (tid == 0) {
        unsigned used = 0;
        for (int r = 0; r < 5; ++r) {
            float best = -1.f; int bi = 0;
            for (int j = 0; j < N_; ++j) {
                if (used & (1u << j)) continue;
                if (sadj[j] > best) { best = sadj[j]; bi = j; }
            }
            used |= (1u << bi);
        }
        float rs = 0.f;
        for (int j = 0; j < N_; ++j) {
            float m = ((used >> j) & 1u) ? sadj[j] : 0.f;
            sA[j] = m; rs += m;
        }
        s_rs = rs;
    }
    __syncthreads();
    const float* Pb = nbuf + (size_t)b * N_ * DP;
    const float* Rr = nbuf + (size_t)NROWS * DP + (size_t)row * DP;
    const float rs = s_rs;
    #pragma unroll
    for (int pass = 0; pass < 2; ++pass) {
        int o = tid + pass * 256;
        if (o < D_) {
            float m = 0.f;
            #pragma unroll
            for (int s = 0; s < N_; ++s) m += sA[s] * Pb[(size_t)s * DP + o];
            out[(size_t)row * D_ + o] =
                lrelu((m + rs * (bn[o] + eemb[o])) * 0.2f + Rr[o] + br[o]);
        }
    }
}

// ---------------------------------------------------------------------------
// Fallback fp32 node kernel (if ws too small for nbuf)
__global__ __launch_bounds__(320) void node_kernel(
    const float* __restrict__ xin, const float* __restrict__ A,
    const float* __restrict__ wn, const float* __restrict__ bn,
    const float* __restrict__ wr, const float* __restrict__ br,
    const float* __restrict__ eemb, float* __restrict__ out)
{
    const int b = blockIdx.x;
    const int tid = threadIdx.x;
    __shared__ float sx[N_][304];
    __shared__ float sA[N_][24];
    __shared__ float srs[N_];

    const float* xb = xin + (size_t)b * N_ * D_;
    for (int it = tid; it < N_ * D_; it += 320) {
        int j = it / D_, d = it - (it / D_) * D_;
        sx[j][d] = xb[it];
    }
    for (int it = tid; it < N_ * N_; it += 320) {
        int t = it / N_, s = it - (it / N_) * N_;
        sA[t][s] = A[((size_t)b * N_ + t) * N_ + s];
    }
    __syncthreads();
    if (tid < N_) {
        float s = 0.f;
        #pragma unroll
        for (int j = 0; j < N_; ++j) s += sA[tid][j];
        srs[tid] = s;
    }
    __syncthreads();

    const int o = tid;
    if (o < D_) {
        float nacc[N_], racc[N_];
        #pragma unroll
        for (int j = 0; j < N_; ++j) { nacc[j] = 0.f; racc[j] = 0.f; }
        const float* wnr = wn + (size_t)o * D_;
        const float* wrr = wr + (size_t)o * D_;
        for (int k4 = 0; k4 < D_; k4 += 4) {
            float4 wn4 = *(const float4*)(wnr + k4);
            float4 wr4 = *(const float4*)(wrr + k4);
            #pragma unroll
            for (int j = 0; j < N_; ++j) {
                float4 xv = *(const float4*)(&sx[j][k4]);
                nacc[j] += wn4.x * xv.x; nacc[j] += wn4.y * xv.y;
                nacc[j] += wn4.z * xv.z; nacc[j] += wn4.w * xv.w;
                racc[j] += wr4.x * xv.x; racc[j] += wr4.y * xv.y;
                racc[j] += wr4.z * xv.z; racc[j] += wr4.w * xv.w;
            }
        }
        const float bn_o = bn[o], br_o = br[o], e0_o = eemb[o];
        const float add_o = bn_o + e0_o;
        #pragma unroll
        for (int t = 0; t < N_; ++t) {
            float m = 0.f;
            #pragma unroll
            for (int s = 0; s < N_; ++s) m += sA[t][s] * nacc[s];
            out[((size_t)b * N_ + t) * D_ + o] =
                lrelu((m + srs[t] * add_o) * 0.2f + racc[t] + br_o);
        }
    }
}

// ---------------------------------------------------------------------------
extern "C" void kernel_launch(void* const* d_in, const int* in_sizes, int n_in,
                              void* d_out, int out_size, void* d_ws, size_t ws_size,
                              hipStream_t stream)
{
    const float* x0 = (const float*)d_in[0];
    auto L = [&](int l, int k) { return (const float*)d_in[1 + l * 10 + k]; };

    // ws layout:
    //   adjraw @0        (225,792)
    //   A      @256KB    (225,792)               (fallback only)
    //   edge w @512KB    (2 x 512KB)             -> ends 1,572,864
    //   node w @1.5MB    (2 x 819,200)           -> ends 3,211,264
    //   nbuf   @3,211,264 (6,881,280)            -> ends 10,092,544
    float* adjraw = (float*)d_ws;
    float* A      = (float*)((char*)d_ws + 262144);
    unsigned short* ewb = (unsigned short*)((char*)d_ws + 524288);
    unsigned short* nwb = (unsigned short*)((char*)d_ws + 1572864);
    float* nbuf   = (float*)((char*)d_ws + 3211264);
    const size_t WS_NEED = 10092544;
    const bool newnode = (ws_size >= WS_NEED);

    prep_all<<<2624, 256, 0, stream>>>(
        L(0,0), L(0,1), L(0,2), L(1,0), L(1,1), L(1,2),
        L(0,5), L(0,7), L(1,5), L(1,7), ewb, nwb, newnode ? 1 : 0);

    for (int l = 0; l < 2; ++l) {
        const float* xin = (l == 0) ? x0 : (const float*)d_out;
        unsigned short* blk = ewb + (size_t)l * 262144;
        edge_mfma<<<GRID_E, 256, 0, stream>>>(xin,
            blk, blk + 81920, blk + 163840, blk + 196608, blk + 229376, blk + 245760,
            L(l, 3), L(l, 4), adjraw);
        if (newnode) {
            unsigned short* nblk = nwb + (size_t)l * 409600;
            node_gemm<<<dim3(NROWS / 16, 2), 256, 0, stream>>>(
                xin, nblk, nblk + 102400, nblk + 204800, nblk + 307200, nbuf);
            node_combine<<<NROWS, 256, 0, stream>>>(adjraw, nbuf, L(l, 6), L(l, 8),
                                                    L(l, 9), (float*)d_out);
        } else {
            topk_kernel<<<NROWS, 64, 0, stream>>>(adjraw, A);
            node_kernel<<<B_, 320, 0, stream>>>(xin, A, L(l, 5), L(l, 6), L(l, 7),
                                                L(l, 8), L(l, 9), (float*)d_out);
        }
    }
}

// Round 11
// 177.452 us; speedup vs baseline: 1.9272x; 1.0002x over previous
//
#include <hip/hip_runtime.h>
#include <math.h>

#define B_  128
#define N_  21
#define D_  300
#define NPAIRS 231                  // upper-tri incl diag
#define NPAIR_TOT (B_ * NPAIRS)     // 29568
#define GRID_E (NPAIR_TOT / 64)     // 462 blocks x 4 waves x 16 pairs
#define NROWS (B_ * N_)             // 2688
#define DP  320

typedef __attribute__((ext_vector_type(8))) short short8v;
typedef __attribute__((ext_vector_type(4))) float f32x4;

__device__ __forceinline__ float lrelu(float v) { return v > 0.f ? v : 0.01f * v; }

__device__ __forceinline__ unsigned short f2bf(float f) {
    unsigned u = __builtin_bit_cast(unsigned, f);
    u += 0x7FFFu + ((u >> 16) & 1u);
    return (unsigned short)(u >> 16);
}
__device__ __forceinline__ float bf2f(unsigned short h) {
    unsigned u = ((unsigned)h) << 16;
    return __builtin_bit_cast(float, u);
}

// ---------------------------------------------------------------------------
// One prep kernel: edge weights (2 layers) + node weights -> bf16 hi/lo.
__global__ __launch_bounds__(256) void prep_all(
    const float* __restrict__ e00, const float* __restrict__ e01, const float* __restrict__ e02,
    const float* __restrict__ e10, const float* __restrict__ e11, const float* __restrict__ e12,
    const float* __restrict__ n0n, const float* __restrict__ n0r,
    const float* __restrict__ n1n, const float* __restrict__ n1r,
    unsigned short* __restrict__ ewb, unsigned short* __restrict__ nwb, int do_node)
{
    int idx = blockIdx.x * 256 + threadIdx.x;   // grid 2624 -> 671744 exact
    float v; unsigned short *ph, *pl; int off;
    if (idx < 262144) {
        int l = idx >> 17;
        int t = idx & 131071;
        unsigned short* blk = ewb + (size_t)l * 262144;
        const float* w0 = l ? e10 : e00;
        const float* w1 = l ? e11 : e01;
        const float* w2 = l ? e12 : e02;
        if (t < 81920) {
            int n = t / 320, k = t - n * 320;
            v = (k < 300) ? w0[n * 300 + k] : 0.f;
            ph = blk; pl = blk + 81920; off = t;
        } else if (t < 114688) {
            int r = t - 81920; v = w1[r];
            ph = blk + 163840; pl = blk + 196608; off = r;
        } else {
            int r = t - 114688; v = w2[r];
            ph = blk + 229376; pl = blk + 245760; off = r;
        }
    } else {
        if (!do_node) return;
        int t = idx - 262144;                    // 0 .. 409599
        int l = t / 204800;
        int r = t - l * 204800;
        int mat = r / 102400;
        int q = r - mat * 102400;
        int n = q / 320, k = q - n * 320;
        const float* src = l ? (mat ? n1r : n1n) : (mat ? n0r : n0n);
        v = (n < 300 && k < 300) ? src[n * 300 + k] : 0.f;
        unsigned short* blk = nwb + (size_t)l * 409600;
        ph = blk + mat * 204800; pl = ph + 102400; off = q;
    }
    unsigned short hb = f2bf(v);
    ph[off] = hb; pl[off] = f2bf(v - bf2f(hb));
}

// ---------------------------------------------------------------------------
// 4-lane-group transpose (by value; verified rounds 6-9).
__device__ __forceinline__ short8v mk_frag(uint2 tlo, uint2 thi,
                                           int s1, int s2, bool hif)
{
    unsigned a0 = (unsigned)__shfl((int)tlo.x, s1);
    unsigned b0 = (unsigned)__shfl((int)thi.x, s1);
    unsigned a1 = (unsigned)__shfl((int)tlo.y, s1);
    unsigned b1 = (unsigned)__shfl((int)thi.y, s1);
    unsigned a2 = (unsigned)__shfl((int)tlo.x, s2);
    unsigned b2 = (unsigned)__shfl((int)thi.x, s2);
    unsigned a3 = (unsigned)__shfl((int)tlo.y, s2);
    unsigned b3 = (unsigned)__shfl((int)thi.y, s2);
    union { unsigned u[4]; short8v v; } r;
    r.u[0] = hif ? b0 : a0; r.u[1] = hif ? b1 : a1;
    r.u[2] = hif ? b2 : a2; r.u[3] = hif ? b3 : a3;
    return r.v;
}

// ---------------------------------------------------------------------------
// Edge MLP: 4 waves x 16 pairs; weights staged per-k-chunk into LDS dbuf via
// global_load_lds (shared across waves), tile-major slot layout (linear dest,
// conflict-free b128 reads). G2/G3 chunk loops FULLY UNROLLED so the packed
// h0/h1 register arrays are statically indexed (rule #20: no scratch).
__global__ __launch_bounds__(256, 2) void edge_mfma(
    const float* __restrict__ x,
    const unsigned short* __restrict__ w0h, const unsigned short* __restrict__ w0l,
    const unsigned short* __restrict__ w1h, const unsigned short* __restrict__ w1l,
    const unsigned short* __restrict__ w2h, const unsigned short* __restrict__ w2l,
    const float* __restrict__ wo, const float* __restrict__ bo,
    float* __restrict__ adjraw)
{
    // [sel][hi: 0..8191 | lo: 8192..16383] ushorts; 2 x 32 KB = 64 KB
    __shared__ __align__(16) unsigned short ldsW[2][16384];

    const int tid  = threadIdx.x;
    const int lane = tid & 63;
    const int w    = tid >> 6;
    const int l15  = lane & 15;
    const int l4   = lane >> 4;

    // this lane-column's pair
    const int p = blockIdx.x * 64 + w * 16 + l15;
    int bb = p / NPAIRS;
    int u  = p - bb * NPAIRS;
    int ii = 0;
    while (u >= N_ - ii) { u -= N_ - ii; ++ii; }
    int jj = ii + u;
    const float* xi = x + ((size_t)bb * N_ + ii) * D_;
    const float* xj = x + ((size_t)bb * N_ + jj) * D_;

    const int s1 = (lane & 15) | ((lane & 16) << 1);
    const int s2 = s1 + 16;
    const bool hif = (l4 >> 1) != 0;

    auto stage_g1 = [&](int c, int sel) {
        #pragma unroll
        for (int i = 0; i < 4; ++i) {
            const int tile = i * 4 + w;
            const size_t g = (size_t)(tile * 16 + l15) * 320 + c * 32 + l4 * 8;
            __builtin_amdgcn_global_load_lds((const unsigned int*)(w0h + g),
                (unsigned int*)(&ldsW[sel][tile * 512]), 16, 0, 0);
            __builtin_amdgcn_global_load_lds((const unsigned int*)(w0l + g),
                (unsigned int*)(&ldsW[sel][8192 + tile * 512]), 16, 0, 0);
        }
    };
    auto stage_g2 = [&](int c, int sel) {
        #pragma unroll
        for (int i = 0; i < 2; ++i) {
            const int tile = i * 4 + w;
            const size_t g = (size_t)(tile * 16 + l15) * 256 + c * 32 + l4 * 8;
            __builtin_amdgcn_global_load_lds((const unsigned int*)(w1h + g),
                (unsigned int*)(&ldsW[sel][tile * 512]), 16, 0, 0);
            __builtin_amdgcn_global_load_lds((const unsigned int*)(w1l + g),
                (unsigned int*)(&ldsW[sel][8192 + tile * 512]), 16, 0, 0);
        }
    };
    auto stage_g3 = [&](int c, int sel) {
        #pragma unroll
        for (int i = 0; i < 2; ++i) {
            const int tile = i * 4 + w;
            const size_t g = (size_t)(tile * 16 + l15) * 128 + c * 32 + l4 * 8;
            __builtin_amdgcn_global_load_lds((const unsigned int*)(w2h + g),
                (unsigned int*)(&ldsW[sel][tile * 512]), 16, 0, 0);
            __builtin_amdgcn_global_load_lds((const unsigned int*)(w2l + g),
                (unsigned int*)(&ldsW[sel][8192 + tile * 512]), 16, 0, 0);
        }
    };

    // ---------------- G1: h0 = w0 @ xij^T, K=320 (10 chunks) ----------------
    f32x4 acc[16];
    #pragma unroll
    for (int t = 0; t < 16; ++t) acc[t] = (f32x4){0.f, 0.f, 0.f, 0.f};

    stage_g1(0, 0);
    __syncthreads();   // implicit vmcnt(0) drain -> buf0 ready

    #pragma unroll 1
    for (int c = 0; c < 10; ++c) {
        const int sel = c & 1;
        if (c < 9) stage_g1(c + 1, sel ^ 1);
        else       stage_g2(0, sel ^ 1);          // pre-stage G2 chunk 0

        // activation fragment for chunk c (overlaps staging latency)
        const int d0 = c * 32 + l4 * 8;
        float v[8];
        if (c < 9) {
            float4 a0 = *(const float4*)(xi + d0);
            float4 a1 = *(const float4*)(xi + d0 + 4);
            float4 b0 = *(const float4*)(xj + d0);
            float4 b1 = *(const float4*)(xj + d0 + 4);
            #pragma unroll
            for (int e = 0; e < 4; ++e) {
                v[e]     = expf(-fabsf((&a0.x)[e] - (&b0.x)[e]));
                v[4 + e] = expf(-fabsf((&a1.x)[e] - (&b1.x)[e]));
            }
        } else {
            #pragma unroll
            for (int e = 0; e < 8; ++e) {
                int d = d0 + e;
                v[e] = (d < D_) ? expf(-fabsf(xi[d] - xj[d])) : 0.f;
            }
        }
        short8v bh, bl;
        #pragma unroll
        for (int e = 0; e < 8; ++e) {
            unsigned short hb = f2bf(v[e]);
            bh[e] = (short)hb;
            bl[e] = (short)f2bf(v[e] - bf2f(hb));
        }

        #pragma unroll
        for (int t = 0; t < 16; ++t) {
            short8v wh = *(const short8v*)(&ldsW[sel][t * 512 + lane * 8]);
            short8v wl = *(const short8v*)(&ldsW[sel][8192 + t * 512 + lane * 8]);
            acc[t] = __builtin_amdgcn_mfma_f32_16x16x32_bf16(wh, bh, acc[t], 0, 0, 0);
            acc[t] = __builtin_amdgcn_mfma_f32_16x16x32_bf16(wh, bl, acc[t], 0, 0, 0);
            acc[t] = __builtin_amdgcn_mfma_f32_16x16x32_bf16(wl, bh, acc[t], 0, 0, 0);
        }
        __syncthreads();   // drains staging (vmcnt0) + all reads of sel done
    }

    // pack h0 -> bf16 hi/lo (static indices throughout)
    uint2 hh[16], ll[16];
    #pragma unroll
    for (int t = 0; t < 16; ++t) {
        unsigned short h_[4], l_[4];
        #pragma unroll
        for (int r = 0; r < 4; ++r) {
            float f = lrelu(acc[t][r]);
            h_[r] = f2bf(f);
            l_[r] = f2bf(f - bf2f(h_[r]));
        }
        hh[t].x = (unsigned)h_[0] | ((unsigned)h_[1] << 16);
        hh[t].y = (unsigned)h_[2] | ((unsigned)h_[3] << 16);
        ll[t].x = (unsigned)l_[0] | ((unsigned)l_[1] << 16);
        ll[t].y = (unsigned)l_[2] | ((unsigned)l_[3] << 16);
    }

    // ---------------- G2: h1 = w1 @ h0^T, K=256 (8 chunks, FULL UNROLL) ----
    f32x4 acc2[8];
    #pragma unroll
    for (int t = 0; t < 8; ++t) acc2[t] = (f32x4){0.f, 0.f, 0.f, 0.f};

    #pragma unroll
    for (int ks = 0; ks < 8; ++ks) {
        const int sel = ks & 1;
        if (ks < 7) stage_g2(ks + 1, sel ^ 1);
        else        stage_g3(0, sel ^ 1);         // pre-stage G3 chunk 0

        short8v bh = mk_frag(hh[2 * ks], hh[2 * ks + 1], s1, s2, hif);
        short8v bl = mk_frag(ll[2 * ks], ll[2 * ks + 1], s1, s2, hif);

        #pragma unroll
        for (int t = 0; t < 8; ++t) {
            short8v wh = *(const short8v*)(&ldsW[sel][t * 512 + lane * 8]);
            short8v wl = *(const short8v*)(&ldsW[sel][8192 + t * 512 + lane * 8]);
            acc2[t] = __builtin_amdgcn_mfma_f32_16x16x32_bf16(wh, bh, acc2[t], 0, 0, 0);
            acc2[t] = __builtin_amdgcn_mfma_f32_16x16x32_bf16(wh, bl, acc2[t], 0, 0, 0);
            acc2[t] = __builtin_amdgcn_mfma_f32_16x16x32_bf16(wl, bh, acc2[t], 0, 0, 0);
        }
        __syncthreads();
    }

    // pack h1
    uint2 hh1[8], ll1[8];
    #pragma unroll
    for (int t = 0; t < 8; ++t) {
        unsigned short h_[4], l_[4];
        #pragma unroll
        for (int r = 0; r < 4; ++r) {
            float f = lrelu(acc2[t][r]);
            h_[r] = f2bf(f);
            l_[r] = f2bf(f - bf2f(h_[r]));
        }
        hh1[t].x = (unsigned)h_[0] | ((unsigned)h_[1] << 16);
        hh1[t].y = (unsigned)h_[2] | ((unsigned)h_[3] << 16);
        ll1[t].x = (unsigned)l_[0] | ((unsigned)l_[1] << 16);
        ll1[t].y = (unsigned)l_[2] | ((unsigned)l_[3] << 16);
    }

    // ---------------- G3: h2 = w2 @ h1^T, K=128 (4 chunks, FULL UNROLL) ----
    f32x4 acc3[8];
    #pragma unroll
    for (int t = 0; t < 8; ++t) acc3[t] = (f32x4){0.f, 0.f, 0.f, 0.f};

    #pragma unroll
    for (int ks = 0; ks < 4; ++ks) {
        const int sel = ks & 1;
        if (ks < 3) stage_g3(ks + 1, sel ^ 1);

        short8v bh = mk_frag(hh1[2 * ks], hh1[2 * ks + 1], s1, s2, hif);
        short8v bl = mk_frag(ll1[2 * ks], ll1[2 * ks + 1], s1, s2, hif);

        #pragma unroll
        for (int t = 0; t < 8; ++t) {
            short8v wh = *(const short8v*)(&ldsW[sel][t * 512 + lane * 8]);
            short8v wl = *(const short8v*)(&ldsW[sel][8192 + t * 512 + lane * 8]);
            acc3[t] = __builtin_amdgcn_mfma_f32_16x16x32_bf16(wh, bh, acc3[t], 0, 0, 0);
            acc3[t] = __builtin_amdgcn_mfma_f32_16x16x32_bf16(wh, bl, acc3[t], 0, 0, 0);
            acc3[t] = __builtin_amdgcn_mfma_f32_16x16x32_bf16(wl, bh, acc3[t], 0, 0, 0);
        }
        __syncthreads();
    }

    // ---------------- sim: in-register reduce over 128 channels ------------
    float ps = 0.f;
    #pragma unroll
    for (int t = 0; t < 8; ++t) {
        float4 wov = *(const float4*)(wo + t * 16 + l4 * 4);
        #pragma unroll
        for (int r = 0; r < 4; ++r)
            ps += lrelu(acc3[t][r]) * (&wov.x)[r];
    }
    ps += __shfl_xor(ps, 16);
    ps += __shfl_xor(ps, 32);
    if (l4 == 0) {
        float a = 1.f / (1.f + expf(-(ps + bo[0])));
        if (ii == jj) a = 0.f;
        adjraw[(size_t)bb * 441 + ii * 21 + jj] = a;
        adjraw[(size_t)bb * 441 + jj * 21 + ii] = a;
    }
}

// ---------------------------------------------------------------------------
// top-5 per row (fallback path only)
__global__ __launch_bounds__(64) void topk_kernel(
    const float* __restrict__ adjraw, float* __restrict__ A)
{
    const int row = blockIdx.x;
    const int lane = threadIdx.x;
    __shared__ float sadj[32];
    __shared__ unsigned s_used;
    if (lane < N_) sadj[lane] = adjraw[row * N_ + lane];
    __syncthreads();
    if (lane == 0) {
        unsigned used = 0;
        for (int r = 0; r < 5; ++r) {
            float best = -1.f; int bi = 0;
            for (int j = 0; j < N_; ++j) {
                if (used & (1u << j)) continue;
                if (sadj[j] > best) { best = sadj[j]; bi = j; }
            }
            used |= (1u << bi);
        }
        s_used = used;
    }
    __syncthreads();
    if (lane < N_)
        A[row * N_ + lane] = ((s_used >> lane) & 1u) ? sadj[lane] : 0.f;
}

// ---------------------------------------------------------------------------
// Node GEMM via MFMA: P = x@wn^T and R = x@wr^T, M=2688 rows.
__global__ __launch_bounds__(256, 4) void node_gemm(
    const float* __restrict__ xin,
    const unsigned short* __restrict__ wnh, const unsigned short* __restrict__ wnl,
    const unsigned short* __restrict__ wrh, const unsigned short* __restrict__ wrl,
    float* __restrict__ nbuf)
{
    __shared__ __align__(16) unsigned short sxh[2][512], sxl[2][512];

    const int tid  = threadIdx.x;
    const int lane = tid & 63;
    const int w    = tid >> 6;
    const int l15  = lane & 15;
    const int l4   = lane >> 4;
    const int M0   = blockIdx.x * 16;
    const int mat  = blockIdx.y;

    const unsigned short* ah_base = mat ? wrh : wnh;
    const unsigned short* al_base = mat ? wrl : wnl;
    float* ob = nbuf + (size_t)mat * NROWS * DP;

    const int sm = tid >> 4;
    const int sk = (tid & 15) * 2;
    const float* xrow = xin + (size_t)(M0 + sm) * D_;
    const int sa = sm * 32 + (((sk >> 3) ^ ((sm >> 1) & 3)) << 3) + (sk & 7);
    const int xr_off = l15 * 32 + ((l4 ^ ((l15 >> 1) & 3)) << 3);

    f32x4 acc[5];
    #pragma unroll
    for (int t = 0; t < 5; ++t) acc[t] = (f32x4){0.f, 0.f, 0.f, 0.f};

    {
        float2 v = *(const float2*)(xrow + sk);
        unsigned short h0 = f2bf(v.x), h1 = f2bf(v.y);
        unsigned uh = (unsigned)h0 | ((unsigned)h1 << 16);
        unsigned ul = (unsigned)f2bf(v.x - bf2f(h0)) |
                      ((unsigned)f2bf(v.y - bf2f(h1)) << 16);
        *(unsigned*)(&sxh[0][sa]) = uh;
        *(unsigned*)(&sxl[0][sa]) = ul;
    }
    __syncthreads();

    #pragma unroll 1
    for (int c = 0; c < 10; ++c) {
        const int sel = c & 1;
        short8v wh[5], wl[5];
        const int kg = c * 32 + l4 * 8;
        #pragma unroll
        for (int t = 0; t < 5; ++t) {
            const size_t n = (size_t)((w * 5 + t) * 16 + l15);
            wh[t] = *(const short8v*)(ah_base + n * DP + kg);
            wl[t] = *(const short8v*)(al_base + n * DP + kg);
        }
        float2 xv; bool have = false;
        if (c < 9) {
            const int k0 = (c + 1) * 32 + sk;
            if (k0 < D_) { xv = *(const float2*)(xrow + k0); have = true; }
        }
        short8v bh = *(const short8v*)(sxh[sel] + xr_off);
        short8v bl = *(const short8v*)(sxl[sel] + xr_off);
        #pragma unroll
        for (int t = 0; t < 5; ++t) {
            acc[t] = __builtin_amdgcn_mfma_f32_16x16x32_bf16(wh[t], bh, acc[t], 0, 0, 0);
            acc[t] = __builtin_amdgcn_mfma_f32_16x16x32_bf16(wh[t], bl, acc[t], 0, 0, 0);
            acc[t] = __builtin_amdgcn_mfma_f32_16x16x32_bf16(wl[t], bh, acc[t], 0, 0, 0);
        }
        if (c < 9) {
            unsigned uh = 0, ul = 0;
            if (have) {
                unsigned short h0 = f2bf(xv.x), h1 = f2bf(xv.y);
                uh = (unsigned)h0 | ((unsigned)h1 << 16);
                ul = (unsigned)f2bf(xv.x - bf2f(h0)) |
                     ((unsigned)f2bf(xv.y - bf2f(h1)) << 16);
            }
            *(unsigned*)(&sxh[sel ^ 1][sa]) = uh;
            *(unsigned*)(&sxl[sel ^ 1][sa]) = ul;
        }
        __syncthreads();
    }

    #pragma unroll
    for (int t = 0; t < 5; ++t) {
        const int n0 = (w * 5 + t) * 16 + l4 * 4;
        float4 v;
        v.x = acc[t][0]; v.y = acc[t][1]; v.z = acc[t][2]; v.w = acc[t][3];
        *(float4*)(ob + (size_t)(M0 + l15) * DP + n0) = v;
    }
}

// ---------------------------------------------------------------------------
// Fused top-k + combine: out = lrelu((A@P + rs*(bn+e0))*0.2 + R + br)
__global__ __launch_bounds__(256) void node_combine(
    const float* __restrict__ adjraw, const float* __restrict__ nbuf,
    const float* __restrict__ bn, const float* __restrict__ br,
    const float* __restrict__ eemb, float* __restrict__ out)
{
    const int row = blockIdx.x;           // 0..2687
    const int b = row / N_;
    const int tid = threadIdx.x;
    __shared__ float sadj[24];
    __shared__ float sA[24];
    __shared__ float s_rs;
    if (tid < N_) sadj[tid] = adjraw[(size_t)row * N_ + tid];
    __syncthreads();
    if (tid == 0) {
        unsigned used = 0;
        for (int r = 0; r < 5; ++r) {
            float best = -1.f; int bi = 0;
            for (int j = 0; j < N_; ++j) {
                if (used & (1u << j)) continue;
                if (sadj[j] > best) { best = sadj[j]; bi = j; }
            }
            used |= (1u << bi);
        }
        float rs = 0.f;
        for (int j = 0; j < N_; ++j) {
            float m = ((used >> j) & 1u) ? sadj[j] : 0.f;
            sA[j] = m; rs += m;
        }
        s_rs = rs;
    }
    __syncthreads();
    const float* Pb = nbuf + (size_t)b * N_ * DP;
    const float* Rr = nbuf + (size_t)NROWS * DP + (size_t)row * DP;
    const float rs = s_rs;
    #pragma unroll
    for (int pass = 0; pass < 2; ++pass) {
        int o = tid + pass * 256;
        if (o < D_) {
            float m = 0.f;
            #pragma unroll
            for (int s = 0; s < N_; ++s) m += sA[s] * Pb[(size_t)s * DP + o];
            out[(size_t)row * D_ + o] =
                lrelu((m + rs * (bn[o] + eemb[o])) * 0.2f + Rr[o] + br[o]);
        }
    }
}

// ---------------------------------------------------------------------------
// Fallback fp32 node kernel (if ws too small for nbuf)
__global__ __launch_bounds__(320) void node_kernel(
    const float* __restrict__ xin, const float* __restrict__ A,
    const float* __restrict__ wn, const float* __restrict__ bn,
    const float* __restrict__ wr, const float* __restrict__ br,
    const float* __restrict__ eemb, float* __restrict__ out)
{
    const int b = blockIdx.x;
    const int tid = threadIdx.x;
    __shared__ float sx[N_][304];
    __shared__ float sA[N_][24];
    __shared__ float srs[N_];

    const float* xb = xin + (size_t)b * N_ * D_;
    for (int it = tid; it < N_ * D_; it += 320) {
        int j = it / D_, d = it - (it / D_) * D_;
        sx[j][d] = xb[it];
    }
    for (int it = tid; it < N_ * N_; it += 320) {
        int t = it / N_, s = it - (it / N_) * N_;
        sA[t][s] = A[((size_t)b * N_ + t) * N_ + s];
    }
    __syncthreads();
    if (tid < N_) {
        float s = 0.f;
        #pragma unroll
        for (int j = 0; j < N_; ++j) s += sA[tid][j];
        srs[tid] = s;
    }
    __syncthreads();

    const int o = tid;
    if (o < D_) {
        float nacc[N_], racc[N_];
        #pragma unroll
        for (int j = 0; j < N_; ++j) { nacc[j] = 0.f; racc[j] = 0.f; }
        const float* wnr = wn + (size_t)o * D_;
        const float* wrr = wr + (size_t)o * D_;
        for (int k4 = 0; k4 < D_; k4 += 4) {
            float4 wn4 = *(const float4*)(wnr + k4);
            float4 wr4 = *(const float4*)(wrr + k4);
            #pragma unroll
            for (int j = 0; j < N_; ++j) {
                float4 xv = *(const float4*)(&sx[j][k4]);
                nacc[j] += wn4.x * xv.x; nacc[j] += wn4.y * xv.y;
                nacc[j] += wn4.z * xv.z; nacc[j] += wn4.w * xv.w;
                racc[j] += wr4.x * xv.x; racc[j] += wr4.y * xv.y;
                racc[j] += wr4.z * xv.z; racc[j] += wr4.w * xv.w;
            }
        }
        const float bn_o = bn[o], br_o = br[o], e0_o = eemb[o];
        const float add_o = bn_o + e0_o;
        #pragma unroll
        for (int t = 0; t < N_; ++t) {
            float m = 0.f;
            #pragma unroll
            for (int s = 0; s < N_; ++s) m += sA[t][s] * nacc[s];
            out[((size_t)b * N_ + t) * D_ + o] =
                lrelu((m + srs[t] * add_o) * 0.2f + racc[t] + br_o);
        }
    }
}

// ---------------------------------------------------------------------------
extern "C" void kernel_launch(void* const* d_in, const int* in_sizes, int n_in,
                              void* d_out, int out_size, void* d_ws, size_t ws_size,
                              hipStream_t stream)
{
    const float* x0 = (const float*)d_in[0];
    auto L = [&](int l, int k) { return (const float*)d_in[1 + l * 10 + k]; };

    // ws layout:
    //   adjraw @0        (225,792)
    //   A      @256KB    (225,792)               (fallback only)
    //   edge w @512KB    (2 x 512KB)             -> ends 1,572,864
    //   node w @1.5MB    (2 x 819,200)           -> ends 3,211,264
    //   nbuf   @3,211,264 (6,881,280)            -> ends 10,092,544
    float* adjraw = (float*)d_ws;
    float* A      = (float*)((char*)d_ws + 262144);
    unsigned short* ewb = (unsigned short*)((char*)d_ws + 524288);
    unsigned short* nwb = (unsigned short*)((char*)d_ws + 1572864);
    float* nbuf   = (float*)((char*)d_ws + 3211264);
    const size_t WS_NEED = 10092544;
    const bool newnode = (ws_size >= WS_NEED);

    prep_all<<<2624, 256, 0, stream>>>(
        L(0,0), L(0,1), L(0,2), L(1,0), L(1,1), L(1,2),
        L(0,5), L(0,7), L(1,5), L(1,7), ewb, nwb, newnode ? 1 : 0);

    for (int l = 0; l < 2; ++l) {
        const float* xin = (l == 0) ? x0 : (const float*)d_out;
        unsigned short* blk = ewb + (size_t)l * 262144;
        edge_mfma<<<GRID_E, 256, 0, stream>>>(xin,
            blk, blk + 81920, blk + 163840, blk + 196608, blk + 229376, blk + 245760,
            L(l, 3), L(l, 4), adjraw);
        if (newnode) {
            unsigned short* nblk = nwb + (size_t)l * 409600;
            node_gemm<<<dim3(NROWS / 16, 2), 256, 0, stream>>>(
                xin, nblk, nblk + 102400, nblk + 204800, nblk + 307200, nbuf);
            node_combine<<<NROWS, 256, 0, stream>>>(adjraw, nbuf, L(l, 6), L(l, 8),
                                                    L(l, 9), (float*)d_out);
        } else {
            topk_kernel<<<NROWS, 64, 0, stream>>>(adjraw, A);
            node_kernel<<<B_, 320, 0, stream>>>(xin, A, L(l, 5), L(l, 6), L(l, 7),
                                                L(l, 8), L(l, 9), (float*)d_out);
        }
    }
}